// Round 1
// baseline (929.774 us; speedup 1.0000x reference)
//
#include <hip/hip_runtime.h>

// ---------- types ----------
typedef __bf16 bf16_t;
typedef bf16_t bf16x8 __attribute__((ext_vector_type(8)));
typedef float f32x4 __attribute__((ext_vector_type(4)));
typedef unsigned short u16;

// ---------- model dims ----------
#define SEQ   2048
#define HID   2048
#define INTER 4096
#define NH    64
#define HD    64
#define CONVD 4352
#define DIN   8512
#define LDP   8576L   // proj leading dim, padded to 67*128
#define CHNK  256
#define NC    8

__device__ __forceinline__ u16 f2bf(float f) {
  union { float f; unsigned u; } a; a.f = f;
  return (u16)((a.u + 0x7fffu + ((a.u >> 16) & 1u)) >> 16);
}

__device__ __forceinline__ void gl2lds16(const void* g, void* l) {
  auto gp = reinterpret_cast<__attribute__((address_space(1))) void*>(
      (unsigned long long)g);
  auto lp = reinterpret_cast<__attribute__((address_space(3))) void*>(
      (unsigned)(unsigned long long)l);
  __builtin_amdgcn_global_load_lds(gp, lp, 16, 0, 0);
}

// ---------- fp32 -> bf16 flat convert ----------
__global__ __launch_bounds__(256) void cvt_bf16(const float* __restrict__ s,
                                                u16* __restrict__ d, int n) {
  int i = blockIdx.x * 256 + threadIdx.x;
  if (i < n) d[i] = f2bf(s[i]);
}

// ---------- transpose + convert: src[R][Cc] fp32 -> dst[n][R] bf16 (n < gridDim.x*32, zero-pad n>=Cc) ----------
__global__ void transpose_bf16(const float* __restrict__ src, u16* __restrict__ dst,
                               int R, int Cc) {
  __shared__ float t[32][33];
  int n0 = blockIdx.x * 32, k0 = blockIdx.y * 32;
  int tx = threadIdx.x, ty = threadIdx.y;
  for (int i = ty; i < 32; i += 8) {
    int n = n0 + tx;
    t[i][tx] = (n < Cc) ? src[(long)(k0 + i) * Cc + n] : 0.f;
  }
  __syncthreads();
  for (int i = ty; i < 32; i += 8)
    dst[(long)(n0 + i) * R + k0 + tx] = f2bf(t[tx][i]);
}

// ---------- bf16 MFMA GEMM: C[M,N] = A[M,K] * Bt[N,K]^T, 128x128 tile, BK=32 ----------
__global__ __launch_bounds__(256, 2) void gemm_bt(const u16* __restrict__ A,
                                                  const u16* __restrict__ Bt,
                                                  float* __restrict__ C,
                                                  int M, int N, int K) {
  __shared__ __align__(16) u16 As[128 * 32];
  __shared__ __align__(16) u16 Bs[128 * 32];
  const int tid = threadIdx.x;
  const int lane = tid & 63;
  const int w = tid >> 6;            // wave 0..3
  const int wm = w >> 1, wn = w & 1; // 2x2 wave grid, 64x64 per wave
  const long bm = blockIdx.y, bn = blockIdx.x;

  f32x4 acc[4][4];
#pragma unroll
  for (int i = 0; i < 4; ++i)
#pragma unroll
    for (int j = 0; j < 4; ++j) acc[i][j] = (f32x4){0.f, 0.f, 0.f, 0.f};

  const int sr = w * 32 + (lane >> 2);   // staging row (pass 0); pass1 = +16
  const int sc = (lane & 3) * 8;         // staging col (elements)
  const u16* Ag = A + bm * 128 * (long)K;
  const u16* Bg = Bt + bn * 128 * (long)K;
  u16* lA0 = As + w * 1024 + lane * 8;
  u16* lA1 = As + w * 1024 + 512 + lane * 8;
  u16* lB0 = Bs + w * 1024 + lane * 8;
  u16* lB1 = Bs + w * 1024 + 512 + lane * 8;
  const int fr = lane & 15, q = lane >> 4;

  for (int k0 = 0; k0 < K; k0 += 32) {
    __syncthreads();
    const u16* a0 = Ag + (long)sr * K + k0 + sc;
    const u16* b0 = Bg + (long)sr * K + k0 + sc;
    gl2lds16(a0, lA0);
    gl2lds16(a0 + 16 * (long)K, lA1);
    gl2lds16(b0, lB0);
    gl2lds16(b0 + 16 * (long)K, lB1);
    __builtin_amdgcn_s_waitcnt(0);
    __syncthreads();
    bf16x8 af[4], bfv[4];
#pragma unroll
    for (int i = 0; i < 4; ++i)
      af[i] = *(const bf16x8*)(As + ((wm * 64 + i * 16 + fr) * 32 + q * 8));
#pragma unroll
    for (int j = 0; j < 4; ++j)
      bfv[j] = *(const bf16x8*)(Bs + ((wn * 64 + j * 16 + fr) * 32 + q * 8));
#pragma unroll
    for (int i = 0; i < 4; ++i)
#pragma unroll
      for (int j = 0; j < 4; ++j)
        acc[i][j] = __builtin_amdgcn_mfma_f32_16x16x32_bf16(af[i], bfv[j], acc[i][j], 0, 0, 0);
  }
  const int cr = (lane >> 4) * 4;
  const int cc = lane & 15;
#pragma unroll
  for (int i = 0; i < 4; ++i)
#pragma unroll
    for (int j = 0; j < 4; ++j) {
      long r = bm * 128 + wm * 64 + i * 16 + cr;
      long cidx = bn * 128 + wn * 64 + j * 16 + cc;
      float* cp = C + r * (long)N + cidx;
#pragma unroll
      for (int t = 0; t < 4; ++t) cp[(long)t * N] = acc[i][j][t];
    }
}

// ---------- depthwise causal conv (K=4) + SiLU over proj[:, 4096:8448] ----------
__global__ __launch_bounds__(256) void conv_silu(const float* __restrict__ proj,
                                                 const float* __restrict__ cw,
                                                 const float* __restrict__ cb,
                                                 float* __restrict__ xBC) {
  int idx = blockIdx.x * 256 + threadIdx.x;   // t*CONVD + c
  int c = idx % CONVD;
  int t = idx / CONVD;
  float acc = cb[c];
#pragma unroll
  for (int k = 0; k < 4; ++k) {
    int tt = t - 3 + k;
    if (tt >= 0) acc += cw[c * 4 + k] * proj[(long)tt * LDP + INTER + c];
  }
  xBC[idx] = acc / (1.f + __expf(-acc));   // SiLU
}

// ---------- dt = softplus(raw + bias), cA = cumsum(dt*A) per chunk ----------
__global__ void dt_cumsum(const float* __restrict__ proj, const float* __restrict__ dtb,
                          const float* __restrict__ A, float* __restrict__ dt,
                          float* __restrict__ cA) {
  int c = blockIdx.x, h = threadIdx.x;
  float bias = dtb[h], a = A[h];
  float acc = 0.f;
  for (int l = 0; l < CHNK; ++l) {
    int t = c * CHNK + l;
    float v = proj[(long)t * LDP + 8448 + h] + bias;
    float sp = (v > 20.f) ? v : log1pf(__expf(v));
    dt[t * NH + h] = sp;
    acc += sp * a;
    cA[t * NH + h] = acc;
  }
}

// ---------- CB[c][l][s] = sum_n C[l,n]*B[s,n]  (group-shared) ----------
__global__ __launch_bounds__(256) void cb_kernel(const float* __restrict__ xBC,
                                                 float* __restrict__ CB) {
  __shared__ __align__(16) float Cst[128][36];   // [n][j], j = l within tile
  int lt = blockIdx.x;     // l-tile (32 l's)
  int c = blockIdx.y;      // chunk
  int tid = threadIdx.x;   // s
  int l0 = lt * 32;
  for (int idx = tid; idx < 4096; idx += 256) {
    int n = idx & 127, j = idx >> 7;
    Cst[n][j] = xBC[(long)(c * 256 + l0 + j) * CONVD + 4224 + n];
  }
  __syncthreads();
  float acc[32];
#pragma unroll
  for (int j = 0; j < 32; ++j) acc[j] = 0.f;
  const float* Brow = xBC + (long)(c * 256 + tid) * CONVD + 4096;
  for (int n = 0; n < 128; ++n) {
    float bv = Brow[n];
#pragma unroll
    for (int jb = 0; jb < 8; ++jb) {
      f32x4 c4 = *(const f32x4*)&Cst[n][jb * 4];
      acc[jb * 4 + 0] += bv * c4.x;
      acc[jb * 4 + 1] += bv * c4.y;
      acc[jb * 4 + 2] += bv * c4.z;
      acc[jb * 4 + 3] += bv * c4.w;
    }
  }
  float* outp = CB + (long)c * 65536 + (long)l0 * 256 + tid;
#pragma unroll
  for (int j = 0; j < 32; ++j) outp[(long)j * 256] = acc[j];
}

// ---------- per-(chunk,head) end-state (transposed [n][p] layout) ----------
__global__ __launch_bounds__(256) void states_kernel(const float* __restrict__ xBC,
                                                     const float* __restrict__ dt,
                                                     const float* __restrict__ cA,
                                                     float* __restrict__ stT) {
  __shared__ float wl[256];
  int c = blockIdx.x, h = blockIdx.y;
  int tid = threadIdx.x;
  int p = tid & 63, ng = tid >> 6;   // n-range = ng*32..+31 (wave-uniform)
  {
    float calast = cA[(long)(c * 256 + 255) * NH + h];
    float ca = cA[(long)(c * 256 + tid) * NH + h];
    wl[tid] = __expf(calast - ca) * dt[(long)(c * 256 + tid) * NH + h];
  }
  __syncthreads();
  float acc[32];
#pragma unroll
  for (int j = 0; j < 32; ++j) acc[j] = 0.f;
  for (int l = 0; l < 256; ++l) {
    const float* row = xBC + (long)(c * 256 + l) * CONVD;
    float t1 = row[h * 64 + p] * wl[l];
#pragma unroll
    for (int jb = 0; jb < 8; ++jb) {
      f32x4 b4 = *(const f32x4*)&row[4096 + ng * 32 + jb * 4];
      acc[jb * 4 + 0] += t1 * b4.x;
      acc[jb * 4 + 1] += t1 * b4.y;
      acc[jb * 4 + 2] += t1 * b4.z;
      acc[jb * 4 + 3] += t1 * b4.w;
    }
  }
  float* outp = stT + ((long)(c * 64 + h) * 128 + ng * 32) * 64 + p;
#pragma unroll
  for (int j = 0; j < 32; ++j) outp[(long)j * 64] = acc[j];
}

// ---------- 8-chunk inter-chunk scan: prevT[c] = state entering chunk c ----------
__global__ __launch_bounds__(256) void scan_kernel(const float* __restrict__ stT,
                                                   const float* __restrict__ cA,
                                                   float* __restrict__ prevT) {
  int id = blockIdx.x * 256 + threadIdx.x;   // h*8192 + n*64 + p
  int h = id >> 13;
  float acc = 0.f;
#pragma unroll
  for (int c = 0; c < NC; ++c) {
    prevT[(long)c * 524288 + id] = acc;
    float cd = __expf(cA[(long)(c * 256 + 255) * NH + h]);
    acc = acc * cd + stT[(long)c * 524288 + id];
  }
}

// ---------- intra-chunk + inter-chunk output + D skip ----------
__global__ __launch_bounds__(256) void ssm_y_kernel(const float* __restrict__ xBC,
                                                    const float* __restrict__ dt,
                                                    const float* __restrict__ cA,
                                                    const float* __restrict__ CB,
                                                    const float* __restrict__ prevT,
                                                    const float* __restrict__ Dp,
                                                    float* __restrict__ Y) {
  __shared__ __align__(16) float xs[256 * 64];
  __shared__ float cas[256];
  __shared__ float dts[256];
  int c = blockIdx.x, h = blockIdx.y;
  int l = threadIdx.x;
  for (int idx = l; idx < 16384; idx += 256) {
    int ll = idx >> 6, p = idx & 63;
    xs[idx] = xBC[(long)(c * 256 + ll) * CONVD + h * 64 + p];
  }
  cas[l] = cA[(long)(c * 256 + l) * NH + h];
  dts[l] = dt[(long)(c * 256 + l) * NH + h];
  __syncthreads();

  float y[64];
#pragma unroll
  for (int p = 0; p < 64; ++p) y[p] = 0.f;

  float cal = cas[l];
  const float* cbrow = CB + (long)c * 65536 + (long)l * 256;
  int send = (l | 63) + 1;   // wave-uniform loop bound
  for (int s4 = 0; s4 < send; s4 += 4) {
    f32x4 cb4 = *(const f32x4*)&cbrow[s4];
#pragma unroll
    for (int u = 0; u < 4; ++u) {
      int s = s4 + u;
      float e = __expf(cal - cas[s]);           // can be inf for s>l: discarded by mask
      float m = (s <= l) ? cb4[u] * e * dts[s] : 0.f;
      const float* xr = &xs[s * 64];
#pragma unroll
      for (int pb = 0; pb < 16; ++pb) {
        f32x4 x4 = *(const f32x4*)&xr[pb * 4];  // broadcast
        y[pb * 4 + 0] += m * x4.x;
        y[pb * 4 + 1] += m * x4.y;
        y[pb * 4 + 2] += m * x4.z;
        y[pb * 4 + 3] += m * x4.w;
      }
    }
  }
  // inter-chunk: y[p] += exp(cA[l]) * sum_n C[l,n] * prev[n][p]
  float ea = __expf(cal);
  const float* crow = xBC + (long)(c * 256 + l) * CONVD + 4224;
  const float* pT = prevT + (long)(c * 64 + h) * 8192;
  for (int n = 0; n < 128; ++n) {
    float cv = ea * crow[n];
#pragma unroll
    for (int pb = 0; pb < 16; ++pb) {
      f32x4 p4 = *(const f32x4*)&pT[n * 64 + pb * 4];  // wave-uniform, L1/L2-hot
      y[pb * 4 + 0] += cv * p4.x;
      y[pb * 4 + 1] += cv * p4.y;
      y[pb * 4 + 2] += cv * p4.z;
      y[pb * 4 + 3] += cv * p4.w;
    }
  }
  // D skip + store
  float dh = Dp[h];
  f32x4* yout = (f32x4*)(Y + (long)(c * 256 + l) * 4096 + h * 64);
#pragma unroll
  for (int pb = 0; pb < 16; ++pb) {
    f32x4 x4 = *(const f32x4*)&xs[l * 64 + pb * 4];
    f32x4 v;
    v.x = y[pb * 4 + 0] + dh * x4.x;
    v.y = y[pb * 4 + 1] + dh * x4.y;
    v.z = y[pb * 4 + 2] + dh * x4.z;
    v.w = y[pb * 4 + 3] + dh * x4.w;
    yout[pb] = v;
  }
}

// ---------- gated RMSNorm -> bf16 z ----------
__global__ __launch_bounds__(256) void rmsnorm_kernel(const float* __restrict__ Y,
                                                      const float* __restrict__ proj,
                                                      const float* __restrict__ nw,
                                                      u16* __restrict__ zbf) {
  __shared__ float red[256];
  int t = blockIdx.x, tid = threadIdx.x;
  const float* y = Y + (long)t * 4096;
  const float* g = proj + (long)t * LDP;
  float zv[16];
  float s = 0.f;
#pragma unroll
  for (int k = 0; k < 16; ++k) {
    int i = tid + k * 256;
    float gv = g[i];
    float z = y[i] * (gv / (1.f + __expf(-gv)));
    zv[k] = z;
    s += z * z;
  }
  red[tid] = s;
  __syncthreads();
  if (tid < 128) red[tid] += red[tid + 128];
  __syncthreads();
  if (tid < 64) {
    float v = red[tid] + red[tid + 64];
    v += __shfl_down(v, 32);
    v += __shfl_down(v, 16);
    v += __shfl_down(v, 8);
    v += __shfl_down(v, 4);
    v += __shfl_down(v, 2);
    v += __shfl_down(v, 1);
    if (tid == 0) red[0] = v;
  }
  __syncthreads();
  float scale = rsqrtf(red[0] * (1.f / 4096.f) + 1e-5f);
#pragma unroll
  for (int k = 0; k < 16; ++k) {
    int i = tid + k * 256;
    zbf[(long)t * 4096 + i] = f2bf(zv[k] * scale * nw[i]);
  }
}

// ---------- launch ----------
extern "C" void kernel_launch(void* const* d_in, const int* in_sizes, int n_in,
                              void* d_out, int out_size, void* d_ws, size_t ws_size,
                              hipStream_t stream) {
  const float* hidden = (const float*)d_in[0];
  const float* Win    = (const float*)d_in[1];
  const float* convw  = (const float*)d_in[2];
  const float* convb  = (const float*)d_in[3];
  const float* dtb    = (const float*)d_in[4];
  const float* Ap     = (const float*)d_in[5];
  const float* Dp     = (const float*)d_in[6];
  const float* nw     = (const float*)d_in[7];
  const float* Wout   = (const float*)d_in[8];
  float* out = (float*)d_out;
  char* ws = (char*)d_ws;

  // workspace layout (bytes); Y overlays hb+WinT (dead after GEMM1)
  u16*   hb    = (u16*)(ws + 0);            //  8,388,608
  u16*   WinT  = (u16*)(ws + 8388608L);     // 35,127,296  [8576][2048] bf16
  float* proj  = (float*)(ws + 43515904L);  // 70,254,592  [2048][8576] f32
  u16*   WoutT = (u16*)(ws + 113770496L);   // 16,777,216  [2048][4096] bf16
  float* xBC   = (float*)(ws + 130547712L); // 35,651,584  [2048][4352] f32
  float* dtv   = (float*)(ws + 166199296L); //    524,288
  float* cAv   = (float*)(ws + 166723584L); //    524,288
  float* CBv   = (float*)(ws + 167247872L); //  2,097,152  [8][256][256]
  float* stT   = (float*)(ws + 169345024L); // 16,777,216  [8][64][128][64]
  float* prevT = (float*)(ws + 186122240L); // 16,777,216
  u16*   zbf   = (u16*)(ws + 202899456L);   // 16,777,216  [2048][4096] bf16
  float* Y     = (float*)(ws + 0);          // 33,554,432  [2048][4096] f32 (overlay)

  cvt_bf16<<<16384, 256, 0, stream>>>(hidden, hb, 4194304);
  transpose_bf16<<<dim3(268, 64), dim3(32, 8), 0, stream>>>(Win, WinT, 2048, 8512);
  transpose_bf16<<<dim3(64, 128), dim3(32, 8), 0, stream>>>(Wout, WoutT, 4096, 2048);
  gemm_bt<<<dim3(67, 16), 256, 0, stream>>>(hb, WinT, proj, 2048, 8576, 2048);
  conv_silu<<<34816, 256, 0, stream>>>(proj, convw, convb, xBC);
  dt_cumsum<<<8, 64, 0, stream>>>(proj, dtb, Ap, dtv, cAv);
  cb_kernel<<<dim3(8, 8), 256, 0, stream>>>(xBC, CBv);
  states_kernel<<<dim3(8, 64), 256, 0, stream>>>(xBC, dtv, cAv, stT);
  scan_kernel<<<2048, 256, 0, stream>>>(stT, cAv, prevT);
  ssm_y_kernel<<<dim3(8, 64), 256, 0, stream>>>(xBC, dtv, cAv, CBv, prevT, Dp, Y);
  rmsnorm_kernel<<<2048, 256, 0, stream>>>(Y, proj, nw, zbf);
  gemm_bt<<<dim3(16, 16), 256, 0, stream>>>(zbf, WoutT, out, 2048, 2048, 4096);
}

// Round 2
// 792.220 us; speedup vs baseline: 1.1736x; 1.1736x over previous
//
#include <hip/hip_runtime.h>

// ---------- types ----------
typedef __bf16 bf16_t;
typedef bf16_t bf16x8 __attribute__((ext_vector_type(8)));
typedef float f32x4 __attribute__((ext_vector_type(4)));
typedef unsigned short u16;

// ---------- model dims ----------
#define SEQ   2048
#define HID   2048
#define INTER 4096
#define NH    64
#define HD    64
#define CONVD 4352
#define DIN   8512
#define LDP   8576L   // proj leading dim, padded to 67*128
#define CHNK  256
#define NC    8

__device__ __forceinline__ u16 f2bf(float f) {
  union { float f; unsigned u; } a; a.f = f;
  return (u16)((a.u + 0x7fffu + ((a.u >> 16) & 1u)) >> 16);
}

__device__ __forceinline__ void gl2lds16(const void* g, void* l) {
  auto gp = reinterpret_cast<__attribute__((address_space(1))) void*>(
      (unsigned long long)g);
  auto lp = reinterpret_cast<__attribute__((address_space(3))) void*>(
      (unsigned)(unsigned long long)l);
  __builtin_amdgcn_global_load_lds(gp, lp, 16, 0, 0);
}

// ---------- fp32 -> bf16 flat convert ----------
__global__ __launch_bounds__(256) void cvt_bf16(const float* __restrict__ s,
                                                u16* __restrict__ d, int n) {
  int i = blockIdx.x * 256 + threadIdx.x;
  if (i < n) d[i] = f2bf(s[i]);
}

// ---------- transpose + convert: src[R][Cc] fp32 -> dst[n][R] bf16 (zero-pad n>=Cc) ----------
__global__ void transpose_bf16(const float* __restrict__ src, u16* __restrict__ dst,
                               int R, int Cc) {
  __shared__ float t[32][33];
  int n0 = blockIdx.x * 32, k0 = blockIdx.y * 32;
  int tx = threadIdx.x, ty = threadIdx.y;
  for (int i = ty; i < 32; i += 8) {
    int n = n0 + tx;
    t[i][tx] = (n < Cc) ? src[(long)(k0 + i) * Cc + n] : 0.f;
  }
  __syncthreads();
  for (int i = ty; i < 32; i += 8)
    dst[(long)(n0 + i) * R + k0 + tx] = f2bf(t[tx][i]);
}

// ---------- bf16 MFMA GEMM: C[M,N] = A[M,K] * Bt[N,K]^T, 128x128 tile, BK=32 ----------
__global__ __launch_bounds__(256, 2) void gemm_bt(const u16* __restrict__ A,
                                                  const u16* __restrict__ Bt,
                                                  float* __restrict__ C,
                                                  int M, int N, int K) {
  __shared__ __align__(16) u16 As[128 * 32];
  __shared__ __align__(16) u16 Bs[128 * 32];
  const int tid = threadIdx.x;
  const int lane = tid & 63;
  const int w = tid >> 6;            // wave 0..3
  const int wm = w >> 1, wn = w & 1; // 2x2 wave grid, 64x64 per wave
  const long bm = blockIdx.y, bn = blockIdx.x;

  f32x4 acc[4][4];
#pragma unroll
  for (int i = 0; i < 4; ++i)
#pragma unroll
    for (int j = 0; j < 4; ++j) acc[i][j] = (f32x4){0.f, 0.f, 0.f, 0.f};

  const int sr = w * 32 + (lane >> 2);   // staging row (pass 0); pass1 = +16
  const int sc = (lane & 3) * 8;         // staging col (elements)
  const u16* Ag = A + bm * 128 * (long)K;
  const u16* Bg = Bt + bn * 128 * (long)K;
  u16* lA0 = As + w * 1024 + lane * 8;
  u16* lA1 = As + w * 1024 + 512 + lane * 8;
  u16* lB0 = Bs + w * 1024 + lane * 8;
  u16* lB1 = Bs + w * 1024 + 512 + lane * 8;
  const int fr = lane & 15, q = lane >> 4;

  for (int k0 = 0; k0 < K; k0 += 32) {
    __syncthreads();
    const u16* a0 = Ag + (long)sr * K + k0 + sc;
    const u16* b0 = Bg + (long)sr * K + k0 + sc;
    gl2lds16(a0, lA0);
    gl2lds16(a0 + 16 * (long)K, lA1);
    gl2lds16(b0, lB0);
    gl2lds16(b0 + 16 * (long)K, lB1);
    __builtin_amdgcn_s_waitcnt(0);
    __syncthreads();
    bf16x8 af[4], bfv[4];
#pragma unroll
    for (int i = 0; i < 4; ++i)
      af[i] = *(const bf16x8*)(As + ((wm * 64 + i * 16 + fr) * 32 + q * 8));
#pragma unroll
    for (int j = 0; j < 4; ++j)
      bfv[j] = *(const bf16x8*)(Bs + ((wn * 64 + j * 16 + fr) * 32 + q * 8));
#pragma unroll
    for (int i = 0; i < 4; ++i)
#pragma unroll
      for (int j = 0; j < 4; ++j)
        acc[i][j] = __builtin_amdgcn_mfma_f32_16x16x32_bf16(af[i], bfv[j], acc[i][j], 0, 0, 0);
  }
  const int cr = (lane >> 4) * 4;
  const int cc = lane & 15;
#pragma unroll
  for (int i = 0; i < 4; ++i)
#pragma unroll
    for (int j = 0; j < 4; ++j) {
      long r = bm * 128 + wm * 64 + i * 16 + cr;
      long cidx = bn * 128 + wn * 64 + j * 16 + cc;
      float* cp = C + r * (long)N + cidx;
#pragma unroll
      for (int t = 0; t < 4; ++t) cp[(long)t * N] = acc[i][j][t];
    }
}

// ---------- depthwise causal conv (K=4) + SiLU over proj[:, 4096:8448] ----------
__global__ __launch_bounds__(256) void conv_silu(const float* __restrict__ proj,
                                                 const float* __restrict__ cw,
                                                 const float* __restrict__ cb,
                                                 float* __restrict__ xBC) {
  int idx = blockIdx.x * 256 + threadIdx.x;   // t*CONVD + c
  int c = idx % CONVD;
  int t = idx / CONVD;
  float acc = cb[c];
#pragma unroll
  for (int k = 0; k < 4; ++k) {
    int tt = t - 3 + k;
    if (tt >= 0) acc += cw[c * 4 + k] * proj[(long)tt * LDP + INTER + c];
  }
  xBC[idx] = acc / (1.f + __expf(-acc));   // SiLU
}

// ---------- dt = softplus(raw + bias), cA = cumsum(dt*A) per chunk ----------
__global__ void dt_cumsum(const float* __restrict__ proj, const float* __restrict__ dtb,
                          const float* __restrict__ A, float* __restrict__ dt,
                          float* __restrict__ cA) {
  int c = blockIdx.x, h = threadIdx.x;
  float bias = dtb[h], a = A[h];
  float acc = 0.f;
  for (int l = 0; l < CHNK; ++l) {
    int t = c * CHNK + l;
    float v = proj[(long)t * LDP + 8448 + h] + bias;
    float sp = (v > 20.f) ? v : log1pf(__expf(v));
    dt[t * NH + h] = sp;
    acc += sp * a;
    cA[t * NH + h] = acc;
  }
}

// ---------- CB[c][l][s] = sum_n C[l,n]*B[s,n]  (group-shared) ----------
__global__ __launch_bounds__(256) void cb_kernel(const float* __restrict__ xBC,
                                                 float* __restrict__ CB) {
  __shared__ __align__(16) float Cst[128][36];   // [n][j], j = l within tile
  int lt = blockIdx.x;     // l-tile (32 l's)
  int c = blockIdx.y;      // chunk
  int tid = threadIdx.x;   // s
  int l0 = lt * 32;
  for (int idx = tid; idx < 4096; idx += 256) {
    int n = idx & 127, j = idx >> 7;
    Cst[n][j] = xBC[(long)(c * 256 + l0 + j) * CONVD + 4224 + n];
  }
  __syncthreads();
  float acc[32];
#pragma unroll
  for (int j = 0; j < 32; ++j) acc[j] = 0.f;
  const float* Brow = xBC + (long)(c * 256 + tid) * CONVD + 4096;
  for (int n = 0; n < 128; ++n) {
    float bv = Brow[n];
#pragma unroll
    for (int jb = 0; jb < 8; ++jb) {
      f32x4 c4 = *(const f32x4*)&Cst[n][jb * 4];
      acc[jb * 4 + 0] += bv * c4.x;
      acc[jb * 4 + 1] += bv * c4.y;
      acc[jb * 4 + 2] += bv * c4.z;
      acc[jb * 4 + 3] += bv * c4.w;
    }
  }
  float* outp = CB + (long)c * 65536 + (long)l0 * 256 + tid;
#pragma unroll
  for (int j = 0; j < 32; ++j) outp[(long)j * 256] = acc[j];
}

// ---------- per-(chunk,head) end-state (transposed [n][p] layout) ----------
__global__ __launch_bounds__(256) void states_kernel(const float* __restrict__ xBC,
                                                     const float* __restrict__ dt,
                                                     const float* __restrict__ cA,
                                                     float* __restrict__ stT) {
  __shared__ float wl[256];
  int c = blockIdx.x, h = blockIdx.y;
  int tid = threadIdx.x;
  int p = tid & 63, ng = tid >> 6;   // n-range = ng*32..+31 (wave-uniform)
  {
    float calast = cA[(long)(c * 256 + 255) * NH + h];
    float ca = cA[(long)(c * 256 + tid) * NH + h];
    wl[tid] = __expf(calast - ca) * dt[(long)(c * 256 + tid) * NH + h];
  }
  __syncthreads();
  float acc[32];
#pragma unroll
  for (int j = 0; j < 32; ++j) acc[j] = 0.f;
  for (int l = 0; l < 256; ++l) {
    const float* row = xBC + (long)(c * 256 + l) * CONVD;
    float t1 = row[h * 64 + p] * wl[l];
#pragma unroll
    for (int jb = 0; jb < 8; ++jb) {
      f32x4 b4 = *(const f32x4*)&row[4096 + ng * 32 + jb * 4];
      acc[jb * 4 + 0] += t1 * b4.x;
      acc[jb * 4 + 1] += t1 * b4.y;
      acc[jb * 4 + 2] += t1 * b4.z;
      acc[jb * 4 + 3] += t1 * b4.w;
    }
  }
  float* outp = stT + ((long)(c * 64 + h) * 128 + ng * 32) * 64 + p;
#pragma unroll
  for (int j = 0; j < 32; ++j) outp[(long)j * 64] = acc[j];
}

// ---------- 8-chunk inter-chunk scan: prevT[c] = state entering chunk c ----------
__global__ __launch_bounds__(256) void scan_kernel(const float* __restrict__ stT,
                                                   const float* __restrict__ cA,
                                                   float* __restrict__ prevT) {
  int id = blockIdx.x * 256 + threadIdx.x;   // h*8192 + n*64 + p
  int h = id >> 13;
  float acc = 0.f;
#pragma unroll
  for (int c = 0; c < NC; ++c) {
    prevT[(long)c * 524288 + id] = acc;
    float cd = __expf(cA[(long)(c * 256 + 255) * NH + h]);
    acc = acc * cd + stT[(long)c * 524288 + id];
  }
}

// ---------- intra+inter SSM output via bf16 MFMA: Y[256x64] = M[256x384] @ X[384x64] ----------
// K-tiles: kt=0..3 intra (s), kt=4..5 inter (n). M computed on the fly -> LDS bf16.
#define LDM 72   // padded leading dim (elements); 144 B rows, 16B-aligned, 2-way bank alias only
__global__ __launch_bounds__(256) void ssm_y_kernel(const float* __restrict__ xBC,
                                                    const float* __restrict__ dt,
                                                    const float* __restrict__ cA,
                                                    const float* __restrict__ CB,
                                                    const float* __restrict__ prevT,
                                                    const float* __restrict__ Dp,
                                                    float* __restrict__ Y) {
  __shared__ __align__(16) u16 Ms[256 * LDM];  // 36864 B
  __shared__ __align__(16) u16 Xt[64 * LDM];   //  9216 B
  __shared__ float cas[256];
  __shared__ float dts[256];
  const int c = blockIdx.x, h = blockIdx.y;
  const int tid = threadIdx.x;
  const int lane = tid & 63;
  const int w = tid >> 6;
  const int fr = lane & 15, q = lane >> 4;

  cas[tid] = cA[(long)(c * 256 + tid) * NH + h];
  dts[tid] = dt[(long)(c * 256 + tid) * NH + h];

  f32x4 acc[4][4];
#pragma unroll
  for (int i = 0; i < 4; ++i)
#pragma unroll
    for (int j = 0; j < 4; ++j) acc[i][j] = (f32x4){0.f, 0.f, 0.f, 0.f};

  const int sg = (tid & 7) * 8;   // M staging: 8-wide k strip
  const int lb = tid >> 3;        // M staging: base row (0..31)
  const int xp = tid & 63;        // X staging: p
  const int xq = tid >> 6;        // X staging: k-quarter

  __syncthreads();

  for (int kt = 0; kt < 6; ++kt) {
    __syncthreads();
    if (kt < 4) {
      const int s0 = kt * 64;
      // ---- stage M tile: M[l][s-s0] = (s<=l) ? CB*exp(cal-cas[s])*dts[s] : 0
      f32x4 e0, e1, d0, d1;
      e0 = *(const f32x4*)&cas[s0 + sg];
      e1 = *(const f32x4*)&cas[s0 + sg + 4];
      d0 = *(const f32x4*)&dts[s0 + sg];
      d1 = *(const f32x4*)&dts[s0 + sg + 4];
#pragma unroll
      for (int k = 0; k < 8; ++k) {
        const int l = lb + 32 * k;
        const float cal = cas[l];
        const float* cb = CB + (long)c * 65536 + (long)l * 256 + s0 + sg;
        f32x4 c0 = *(const f32x4*)cb;
        f32x4 c1 = *(const f32x4*)(cb + 4);
        union { u16 u[8]; bf16x8 v; } pk;
#pragma unroll
        for (int u = 0; u < 8; ++u) {
          int s = s0 + sg + u;
          float cv = (u < 4) ? c0[u] : c1[u - 4];
          float cs = (u < 4) ? e0[u] : e1[u - 4];
          float dv = (u < 4) ? d0[u] : d1[u - 4];
          float m = (s <= l) ? cv * __expf(cal - cs) * dv : 0.f;
          pk.u[u] = f2bf(m);
        }
        *(bf16x8*)(Ms + l * LDM + sg) = pk.v;
      }
      // ---- stage X^T tile: Xt[p][s-s0] = x[s][p]
#pragma unroll
      for (int half = 0; half < 2; ++half) {
        const int sb = xq * 16 + half * 8;
        union { u16 u[8]; bf16x8 v; } pk;
#pragma unroll
        for (int u = 0; u < 8; ++u)
          pk.u[u] = f2bf(xBC[(long)(c * 256 + s0 + sb + u) * CONVD + h * 64 + xp]);
        *(bf16x8*)(Xt + xp * LDM + sb) = pk.v;
      }
    } else {
      const int n0 = (kt - 4) * 64;
      // ---- stage M tile: M[l][n-n0] = exp(cal) * C[l][n]
#pragma unroll
      for (int k = 0; k < 8; ++k) {
        const int l = lb + 32 * k;
        const float ea = __expf(cas[l]);
        const float* cr = xBC + (long)(c * 256 + l) * CONVD + 4224 + n0 + sg;
        f32x4 c0 = *(const f32x4*)cr;
        f32x4 c1 = *(const f32x4*)(cr + 4);
        union { u16 u[8]; bf16x8 v; } pk;
#pragma unroll
        for (int u = 0; u < 8; ++u)
          pk.u[u] = f2bf(ea * ((u < 4) ? c0[u] : c1[u - 4]));
        *(bf16x8*)(Ms + l * LDM + sg) = pk.v;
      }
      // ---- stage X^T tile: Xt[p][n-n0] = prev[n][p]  (prevT is [n][p])
      const float* pT = prevT + (long)(c * 64 + h) * 8192;
#pragma unroll
      for (int half = 0; half < 2; ++half) {
        const int nb = xq * 16 + half * 8;
        union { u16 u[8]; bf16x8 v; } pk;
#pragma unroll
        for (int u = 0; u < 8; ++u)
          pk.u[u] = f2bf(pT[(n0 + nb + u) * 64 + xp]);
        *(bf16x8*)(Xt + xp * LDM + nb) = pk.v;
      }
    }
    __syncthreads();
    // ---- MFMA: 2 k-steps of 32 within the 64-wide tile
#pragma unroll
    for (int ks = 0; ks < 64; ks += 32) {
      bf16x8 af[4], bfv[4];
#pragma unroll
      for (int i = 0; i < 4; ++i)
        af[i] = *(const bf16x8*)(Ms + (w * 64 + i * 16 + fr) * LDM + ks + q * 8);
#pragma unroll
      for (int j = 0; j < 4; ++j)
        bfv[j] = *(const bf16x8*)(Xt + (j * 16 + fr) * LDM + ks + q * 8);
#pragma unroll
      for (int i = 0; i < 4; ++i)
#pragma unroll
        for (int j = 0; j < 4; ++j)
          acc[i][j] = __builtin_amdgcn_mfma_f32_16x16x32_bf16(af[i], bfv[j], acc[i][j], 0, 0, 0);
    }
  }

  // ---- epilogue: Y = acc + D[h]*x, fp32
  const int cr = (lane >> 4) * 4;
  const int cc = lane & 15;
  const float dh = Dp[h];
#pragma unroll
  for (int i = 0; i < 4; ++i)
#pragma unroll
    for (int j = 0; j < 4; ++j) {
      const int p = j * 16 + cc;
#pragma unroll
      for (int t = 0; t < 4; ++t) {
        const int row = w * 64 + i * 16 + cr + t;
        const float xv = xBC[(long)(c * 256 + row) * CONVD + h * 64 + p];
        Y[(long)(c * 256 + row) * 4096 + h * 64 + p] = acc[i][j][t] + dh * xv;
      }
    }
}

// ---------- gated RMSNorm -> bf16 z ----------
__global__ __launch_bounds__(256) void rmsnorm_kernel(const float* __restrict__ Y,
                                                      const float* __restrict__ proj,
                                                      const float* __restrict__ nw,
                                                      u16* __restrict__ zbf) {
  __shared__ float red[256];
  int t = blockIdx.x, tid = threadIdx.x;
  const float* y = Y + (long)t * 4096;
  const float* g = proj + (long)t * LDP;
  float zv[16];
  float s = 0.f;
#pragma unroll
  for (int k = 0; k < 16; ++k) {
    int i = tid + k * 256;
    float gv = g[i];
    float z = y[i] * (gv / (1.f + __expf(-gv)));
    zv[k] = z;
    s += z * z;
  }
  red[tid] = s;
  __syncthreads();
  if (tid < 128) red[tid] += red[tid + 128];
  __syncthreads();
  if (tid < 64) {
    float v = red[tid] + red[tid + 64];
    v += __shfl_down(v, 32);
    v += __shfl_down(v, 16);
    v += __shfl_down(v, 8);
    v += __shfl_down(v, 4);
    v += __shfl_down(v, 2);
    v += __shfl_down(v, 1);
    if (tid == 0) red[0] = v;
  }
  __syncthreads();
  float scale = rsqrtf(red[0] * (1.f / 4096.f) + 1e-5f);
#pragma unroll
  for (int k = 0; k < 16; ++k) {
    int i = tid + k * 256;
    zbf[(long)t * 4096 + i] = f2bf(zv[k] * scale * nw[i]);
  }
}

// ---------- launch ----------
extern "C" void kernel_launch(void* const* d_in, const int* in_sizes, int n_in,
                              void* d_out, int out_size, void* d_ws, size_t ws_size,
                              hipStream_t stream) {
  const float* hidden = (const float*)d_in[0];
  const float* Win    = (const float*)d_in[1];
  const float* convw  = (const float*)d_in[2];
  const float* convb  = (const float*)d_in[3];
  const float* dtb    = (const float*)d_in[4];
  const float* Ap     = (const float*)d_in[5];
  const float* Dp     = (const float*)d_in[6];
  const float* nw     = (const float*)d_in[7];
  const float* Wout   = (const float*)d_in[8];
  float* out = (float*)d_out;
  char* ws = (char*)d_ws;

  // workspace layout (bytes); Y overlays hb+WinT (dead after GEMM1)
  u16*   hb    = (u16*)(ws + 0);            //  8,388,608
  u16*   WinT  = (u16*)(ws + 8388608L);     // 35,127,296  [8576][2048] bf16
  float* proj  = (float*)(ws + 43515904L);  // 70,254,592  [2048][8576] f32
  u16*   WoutT = (u16*)(ws + 113770496L);   // 16,777,216  [2048][4096] bf16
  float* xBC   = (float*)(ws + 130547712L); // 35,651,584  [2048][4352] f32
  float* dtv   = (float*)(ws + 166199296L); //    524,288
  float* cAv   = (float*)(ws + 166723584L); //    524,288
  float* CBv   = (float*)(ws + 167247872L); //  2,097,152  [8][256][256]
  float* stT   = (float*)(ws + 169345024L); // 16,777,216  [8][64][128][64]
  float* prevT = (float*)(ws + 186122240L); // 16,777,216
  u16*   zbf   = (u16*)(ws + 202899456L);   // 16,777,216  [2048][4096] bf16
  float* Y     = (float*)(ws + 0);          // 33,554,432  [2048][4096] f32 (overlay)

  cvt_bf16<<<16384, 256, 0, stream>>>(hidden, hb, 4194304);
  transpose_bf16<<<dim3(268, 64), dim3(32, 8), 0, stream>>>(Win, WinT, 2048, 8512);
  transpose_bf16<<<dim3(64, 128), dim3(32, 8), 0, stream>>>(Wout, WoutT, 4096, 2048);
  gemm_bt<<<dim3(67, 16), 256, 0, stream>>>(hb, WinT, proj, 2048, 8576, 2048);
  conv_silu<<<34816, 256, 0, stream>>>(proj, convw, convb, xBC);
  dt_cumsum<<<8, 64, 0, stream>>>(proj, dtb, Ap, dtv, cAv);
  cb_kernel<<<dim3(8, 8), 256, 0, stream>>>(xBC, CBv);
  states_kernel<<<dim3(8, 64), 256, 0, stream>>>(xBC, dtv, cAv, stT);
  scan_kernel<<<2048, 256, 0, stream>>>(stT, cAv, prevT);
  ssm_y_kernel<<<dim3(8, 64), 256, 0, stream>>>(xBC, dtv, cAv, CBv, prevT, Dp, Y);
  rmsnorm_kernel<<<2048, 256, 0, stream>>>(Y, proj, nw, zbf);
  gemm_bt<<<dim3(16, 16), 256, 0, stream>>>(zbf, WoutT, out, 2048, 2048, 4096);
}

// Round 3
// 505.010 us; speedup vs baseline: 1.8411x; 1.5687x over previous
//
#include <hip/hip_runtime.h>

// ---------- types ----------
typedef __bf16 bf16_t;
typedef bf16_t bf16x8 __attribute__((ext_vector_type(8)));
typedef float f32x4 __attribute__((ext_vector_type(4)));
typedef unsigned short u16;
typedef u16 u16x8 __attribute__((ext_vector_type(8)));

// ---------- model dims ----------
#define SEQ   2048
#define HID   2048
#define INTER 4096
#define NH    64
#define HD    64
#define CONVD 4352
#define DIN   8512
#define LDP   8576L   // proj leading dim, padded to 67*128
#define CHNK  256
#define NC    8

__device__ __forceinline__ u16 f2bf(float f) {
  union { float f; unsigned u; } a; a.f = f;
  return (u16)((a.u + 0x7fffu + ((a.u >> 16) & 1u)) >> 16);
}
__device__ __forceinline__ float bf2f(u16 u) {
  union { unsigned u; float f; } a; a.u = ((unsigned)u) << 16;
  return a.f;
}

__device__ __forceinline__ void gl2lds16(const void* g, void* l) {
  auto gp = reinterpret_cast<__attribute__((address_space(1))) void*>(
      (unsigned long long)g);
  auto lp = reinterpret_cast<__attribute__((address_space(3))) void*>(
      (unsigned)(unsigned long long)l);
  __builtin_amdgcn_global_load_lds(gp, lp, 16, 0, 0);
}

// ---------- fp32 -> bf16 flat convert ----------
__global__ __launch_bounds__(256) void cvt_bf16(const float* __restrict__ s,
                                                u16* __restrict__ d, int n) {
  int i = blockIdx.x * 256 + threadIdx.x;
  if (i < n) d[i] = f2bf(s[i]);
}

// ---------- transpose + convert: src[R][Cc] fp32 -> dst[n][R] bf16 (zero-pad n>=Cc) ----------
__global__ void transpose_bf16(const float* __restrict__ src, u16* __restrict__ dst,
                               int R, int Cc) {
  __shared__ float t[32][33];
  int n0 = blockIdx.x * 32, k0 = blockIdx.y * 32;
  int tx = threadIdx.x, ty = threadIdx.y;
  for (int i = ty; i < 32; i += 8) {
    int n = n0 + tx;
    t[i][tx] = (n < Cc) ? src[(long)(k0 + i) * Cc + n] : 0.f;
  }
  __syncthreads();
  for (int i = ty; i < 32; i += 8)
    dst[(long)(n0 + i) * R + k0 + tx] = f2bf(t[tx][i]);
}

// ---------- u16 transpose: xbf[2048][4352] cols 0..4223 -> xT[4224][2048] ----------
__global__ void transpose_u16k(const u16* __restrict__ src, u16* __restrict__ dst) {
  __shared__ u16 t[32][34];
  int n0 = blockIdx.x * 32, k0 = blockIdx.y * 32;
  int tx = threadIdx.x, ty = threadIdx.y;
  for (int i = ty; i < 32; i += 8)
    t[i][tx] = src[(long)(k0 + i) * CONVD + n0 + tx];
  __syncthreads();
  for (int i = ty; i < 32; i += 8)
    dst[(long)(n0 + i) * 2048 + k0 + tx] = t[tx][i];
}

// ---------- bf16 MFMA GEMM: C[M,N] = A[M,K] * Bt[N,K]^T, 128x128 tile, BK=32 ----------
__global__ __launch_bounds__(256, 2) void gemm_bt(const u16* __restrict__ A,
                                                  const u16* __restrict__ Bt,
                                                  float* __restrict__ C,
                                                  int M, int N, int K) {
  __shared__ __align__(16) u16 As[128 * 32];
  __shared__ __align__(16) u16 Bs[128 * 32];
  const int tid = threadIdx.x;
  const int lane = tid & 63;
  const int w = tid >> 6;
  const int wm = w >> 1, wn = w & 1;
  const long bm = blockIdx.y, bn = blockIdx.x;

  f32x4 acc[4][4];
#pragma unroll
  for (int i = 0; i < 4; ++i)
#pragma unroll
    for (int j = 0; j < 4; ++j) acc[i][j] = (f32x4){0.f, 0.f, 0.f, 0.f};

  const int sr = w * 32 + (lane >> 2);
  const int sc = (lane & 3) * 8;
  const u16* Ag = A + bm * 128 * (long)K;
  const u16* Bg = Bt + bn * 128 * (long)K;
  u16* lA0 = As + w * 1024 + lane * 8;
  u16* lA1 = As + w * 1024 + 512 + lane * 8;
  u16* lB0 = Bs + w * 1024 + lane * 8;
  u16* lB1 = Bs + w * 1024 + 512 + lane * 8;
  const int fr = lane & 15, q = lane >> 4;

  for (int k0 = 0; k0 < K; k0 += 32) {
    __syncthreads();
    const u16* a0 = Ag + (long)sr * K + k0 + sc;
    const u16* b0 = Bg + (long)sr * K + k0 + sc;
    gl2lds16(a0, lA0);
    gl2lds16(a0 + 16 * (long)K, lA1);
    gl2lds16(b0, lB0);
    gl2lds16(b0 + 16 * (long)K, lB1);
    __builtin_amdgcn_s_waitcnt(0);
    __syncthreads();
    bf16x8 af[4], bfv[4];
#pragma unroll
    for (int i = 0; i < 4; ++i)
      af[i] = *(const bf16x8*)(As + ((wm * 64 + i * 16 + fr) * 32 + q * 8));
#pragma unroll
    for (int j = 0; j < 4; ++j)
      bfv[j] = *(const bf16x8*)(Bs + ((wn * 64 + j * 16 + fr) * 32 + q * 8));
#pragma unroll
    for (int i = 0; i < 4; ++i)
#pragma unroll
      for (int j = 0; j < 4; ++j)
        acc[i][j] = __builtin_amdgcn_mfma_f32_16x16x32_bf16(af[i], bfv[j], acc[i][j], 0, 0, 0);
  }
  const int cr = (lane >> 4) * 4;
  const int cc = lane & 15;
#pragma unroll
  for (int i = 0; i < 4; ++i)
#pragma unroll
    for (int j = 0; j < 4; ++j) {
      long r = bm * 128 + wm * 64 + i * 16 + cr;
      long cidx = bn * 128 + wn * 64 + j * 16 + cc;
      float* cp = C + r * (long)N + cidx;
#pragma unroll
      for (int t = 0; t < 4; ++t) cp[(long)t * N] = acc[i][j][t];
    }
}

// ---------- depthwise causal conv (K=4) + SiLU -> bf16 xbf ----------
__global__ __launch_bounds__(256) void conv_silu(const float* __restrict__ proj,
                                                 const float* __restrict__ cw,
                                                 const float* __restrict__ cb,
                                                 u16* __restrict__ xbf) {
  int idx = blockIdx.x * 256 + threadIdx.x;   // t*CONVD + c
  int c = idx % CONVD;
  int t = idx / CONVD;
  float acc = cb[c];
#pragma unroll
  for (int k = 0; k < 4; ++k) {
    int tt = t - 3 + k;
    if (tt >= 0) acc += cw[c * 4 + k] * proj[(long)tt * LDP + INTER + c];
  }
  xbf[idx] = f2bf(acc / (1.f + __expf(-acc)));   // SiLU
}

// ---------- dt softplus + per-chunk cumsum (Hillis-Steele), [h][t] layout ----------
__global__ __launch_bounds__(256) void dt_cumsum(const float* __restrict__ proj,
                                                 const float* __restrict__ dtb,
                                                 const float* __restrict__ A,
                                                 float* __restrict__ dt2,
                                                 float* __restrict__ cA2) {
  __shared__ float sc[256];
  int c = blockIdx.x, h = blockIdx.y, l = threadIdx.x;
  float v = proj[(long)(c * 256 + l) * LDP + 8448 + h] + dtb[h];
  float sp = (v > 20.f) ? v : log1pf(__expf(v));
  dt2[h * 2048 + c * 256 + l] = sp;
  sc[l] = sp * A[h];
  __syncthreads();
  for (int off = 1; off < 256; off <<= 1) {
    float t = (l >= off) ? sc[l - off] : 0.f;
    __syncthreads();
    sc[l] += t;
    __syncthreads();
  }
  cA2[h * 2048 + c * 256 + l] = sc[l];
}

// ---------- CB[c][l][s] = C[l,:].B[s,:] via MFMA, per-chunk strided GEMM ----------
__global__ __launch_bounds__(256, 2) void cb_gemm(const u16* __restrict__ xbf,
                                                  float* __restrict__ CB) {
  __shared__ __align__(16) u16 As[128 * 32];
  __shared__ __align__(16) u16 Bs[128 * 32];
  const int tid = threadIdx.x;
  const int lane = tid & 63;
  const int w = tid >> 6;
  const int wm = w >> 1, wn = w & 1;
  const int bm = blockIdx.y, bn = blockIdx.x, c = blockIdx.z;

  f32x4 acc[4][4];
#pragma unroll
  for (int i = 0; i < 4; ++i)
#pragma unroll
    for (int j = 0; j < 4; ++j) acc[i][j] = (f32x4){0.f, 0.f, 0.f, 0.f};

  const int sr = w * 32 + (lane >> 2);
  const int sc = (lane & 3) * 8;
  const u16* Ag = xbf + (long)(c * 256 + bm * 128) * CONVD + 4224;  // C region
  const u16* Bg = xbf + (long)(c * 256 + bn * 128) * CONVD + 4096;  // B region
  u16* lA0 = As + w * 1024 + lane * 8;
  u16* lA1 = As + w * 1024 + 512 + lane * 8;
  u16* lB0 = Bs + w * 1024 + lane * 8;
  u16* lB1 = Bs + w * 1024 + 512 + lane * 8;
  const int fr = lane & 15, q = lane >> 4;

  for (int k0 = 0; k0 < 128; k0 += 32) {
    __syncthreads();
    const u16* a0 = Ag + (long)sr * CONVD + k0 + sc;
    const u16* b0 = Bg + (long)sr * CONVD + k0 + sc;
    gl2lds16(a0, lA0);
    gl2lds16(a0 + 16L * CONVD, lA1);
    gl2lds16(b0, lB0);
    gl2lds16(b0 + 16L * CONVD, lB1);
    __builtin_amdgcn_s_waitcnt(0);
    __syncthreads();
    bf16x8 af[4], bfv[4];
#pragma unroll
    for (int i = 0; i < 4; ++i)
      af[i] = *(const bf16x8*)(As + ((wm * 64 + i * 16 + fr) * 32 + q * 8));
#pragma unroll
    for (int j = 0; j < 4; ++j)
      bfv[j] = *(const bf16x8*)(Bs + ((wn * 64 + j * 16 + fr) * 32 + q * 8));
#pragma unroll
    for (int i = 0; i < 4; ++i)
#pragma unroll
      for (int j = 0; j < 4; ++j)
        acc[i][j] = __builtin_amdgcn_mfma_f32_16x16x32_bf16(af[i], bfv[j], acc[i][j], 0, 0, 0);
  }
  const int cr = (lane >> 4) * 4;
  const int cc = lane & 15;
  float* Cc = CB + (long)c * 65536;
#pragma unroll
  for (int i = 0; i < 4; ++i)
#pragma unroll
    for (int j = 0; j < 4; ++j) {
      int r = bm * 128 + wm * 64 + i * 16 + cr;
      int cidx = bn * 128 + wn * 64 + j * 16 + cc;
      float* cp = Cc + (long)r * 256 + cidx;
#pragma unroll
      for (int t = 0; t < 4; ++t) cp[t * 256] = acc[i][j][t];
    }
}

// ---------- states via MFMA: stT[n][p] = sum_l (B[l][n]*wl[l]) * x[l][p] ----------
#define LDM 72
__global__ __launch_bounds__(256) void states_kernel(const u16* __restrict__ xT,
                                                     const float* __restrict__ dt2,
                                                     const float* __restrict__ cA2,
                                                     float* __restrict__ stT) {
  __shared__ __align__(16) u16 Ms[128 * LDM];  // Bw [n][l_local]
  __shared__ __align__(16) u16 Xs[64 * LDM];   // x  [p][l_local]
  __shared__ float wl[256];
  const int c = blockIdx.x, h = blockIdx.y;
  const int tid = threadIdx.x;
  const int lane = tid & 63, w = tid >> 6;
  const int fr = lane & 15, q = lane >> 4;
  {
    float calast = cA2[h * 2048 + c * 256 + 255];
    float ca = cA2[h * 2048 + c * 256 + tid];
    wl[tid] = __expf(calast - ca) * dt2[h * 2048 + c * 256 + tid];
  }
  f32x4 acc[2][4];
#pragma unroll
  for (int i = 0; i < 2; ++i)
#pragma unroll
    for (int j = 0; j < 4; ++j) acc[i][j] = (f32x4){0.f, 0.f, 0.f, 0.f};

  const int lc8 = (tid & 7) * 8;
  const int rn = tid >> 3;   // 0..31
  __syncthreads();

  for (int kt = 0; kt < 4; ++kt) {
    __syncthreads();
    // stage A = B * wl, transposed source rows xT[4096+n]
#pragma unroll
    for (int r = 0; r < 4; ++r) {
      int n = rn + 32 * r;
      u16x8 raw = *(const u16x8*)(xT + (long)(4096 + n) * 2048 + c * 256 + kt * 64 + lc8);
      union { u16 u[8]; bf16x8 v; } pk;
#pragma unroll
      for (int u = 0; u < 8; ++u)
        pk.u[u] = f2bf(bf2f(raw[u]) * wl[kt * 64 + lc8 + u]);
      *(bf16x8*)(Ms + n * LDM + lc8) = pk.v;
    }
    // stage X from xT rows h*64+p (already bf16, straight copy)
#pragma unroll
    for (int r = 0; r < 2; ++r) {
      int p = rn + 32 * r;
      *(bf16x8*)(Xs + p * LDM + lc8) =
          *(const bf16x8*)(xT + (long)(h * 64 + p) * 2048 + c * 256 + kt * 64 + lc8);
    }
    __syncthreads();
#pragma unroll
    for (int ks = 0; ks < 64; ks += 32) {
      bf16x8 af[2], xf[4];
#pragma unroll
      for (int i = 0; i < 2; ++i)
        af[i] = *(const bf16x8*)(Ms + (w * 32 + i * 16 + fr) * LDM + ks + q * 8);
#pragma unroll
      for (int j = 0; j < 4; ++j)
        xf[j] = *(const bf16x8*)(Xs + (j * 16 + fr) * LDM + ks + q * 8);
#pragma unroll
      for (int i = 0; i < 2; ++i)
#pragma unroll
        for (int j = 0; j < 4; ++j)
          acc[i][j] = __builtin_amdgcn_mfma_f32_16x16x32_bf16(af[i], xf[j], acc[i][j], 0, 0, 0);
    }
  }
  const int cr = (lane >> 4) * 4;
  const int cc = lane & 15;
  float* outp = stT + (long)(c * 64 + h) * 8192;
#pragma unroll
  for (int i = 0; i < 2; ++i)
#pragma unroll
    for (int j = 0; j < 4; ++j) {
      int n = w * 32 + i * 16 + cr;
      int p = j * 16 + cc;
#pragma unroll
      for (int t = 0; t < 4; ++t) outp[(n + t) * 64 + p] = acc[i][j][t];
    }
}

// ---------- 8-chunk inter-chunk scan ----------
__global__ __launch_bounds__(256) void scan_kernel(const float* __restrict__ stT,
                                                   const float* __restrict__ cA2,
                                                   float* __restrict__ prevT) {
  int id = blockIdx.x * 256 + threadIdx.x;   // h*8192 + n*64 + p
  int h = id >> 13;
  float acc = 0.f;
#pragma unroll
  for (int c = 0; c < NC; ++c) {
    prevT[(long)c * 524288 + id] = acc;
    float cd = __expf(cA2[h * 2048 + c * 256 + 255]);
    acc = acc * cd + stT[(long)c * 524288 + id];
  }
}

// ---------- intra+inter SSM output via bf16 MFMA: Y[256x64] = M[256x384] @ X[384x64] ----------
__global__ __launch_bounds__(256) void ssm_y_kernel(const u16* __restrict__ xbf,
                                                    const u16* __restrict__ xT,
                                                    const float* __restrict__ dt2,
                                                    const float* __restrict__ cA2,
                                                    const float* __restrict__ CB,
                                                    const float* __restrict__ prevT,
                                                    const float* __restrict__ Dp,
                                                    float* __restrict__ Y) {
  __shared__ __align__(16) u16 Ms[256 * LDM];
  __shared__ __align__(16) u16 Xt[64 * LDM];
  __shared__ float cas[256];
  __shared__ float dts[256];
  const int c = blockIdx.x, h = blockIdx.y;
  const int tid = threadIdx.x;
  const int lane = tid & 63;
  const int w = tid >> 6;
  const int fr = lane & 15, q = lane >> 4;

  cas[tid] = cA2[h * 2048 + c * 256 + tid];
  dts[tid] = dt2[h * 2048 + c * 256 + tid];

  f32x4 acc[4][4];
#pragma unroll
  for (int i = 0; i < 4; ++i)
#pragma unroll
    for (int j = 0; j < 4; ++j) acc[i][j] = (f32x4){0.f, 0.f, 0.f, 0.f};

  const int sg = (tid & 7) * 8;   // M staging: 8-wide k strip
  const int lb = tid >> 3;        // M staging: base row (0..31)
  const int xp = tid & 63;        // inter X staging: p
  const int xq = tid >> 6;        // inter X staging: k-quarter

  __syncthreads();

  for (int kt = 0; kt < 6; ++kt) {
    __syncthreads();
    if (kt < 4) {
      const int s0 = kt * 64;
      f32x4 e0 = *(const f32x4*)&cas[s0 + sg];
      f32x4 e1 = *(const f32x4*)&cas[s0 + sg + 4];
      f32x4 d0 = *(const f32x4*)&dts[s0 + sg];
      f32x4 d1 = *(const f32x4*)&dts[s0 + sg + 4];
#pragma unroll
      for (int k = 0; k < 8; ++k) {
        const int l = lb + 32 * k;
        const float cal = cas[l];
        const float* cb = CB + (long)c * 65536 + (long)l * 256 + s0 + sg;
        f32x4 c0 = *(const f32x4*)cb;
        f32x4 c1 = *(const f32x4*)(cb + 4);
        union { u16 u[8]; bf16x8 v; } pk;
#pragma unroll
        for (int u = 0; u < 8; ++u) {
          int s = s0 + sg + u;
          float cv = (u < 4) ? c0[u] : c1[u - 4];
          float cs = (u < 4) ? e0[u] : e1[u - 4];
          float dv = (u < 4) ? d0[u] : d1[u - 4];
          float m = (s <= l) ? cv * __expf(cal - cs) * dv : 0.f;
          pk.u[u] = f2bf(m);
        }
        *(bf16x8*)(Ms + l * LDM + sg) = pk.v;
      }
      // X^T tile: straight bf16 copy from xT
#pragma unroll
      for (int r = 0; r < 2; ++r) {
        int p = (tid >> 3) + 32 * r;
        *(bf16x8*)(Xt + p * LDM + sg) =
            *(const bf16x8*)(xT + (long)(h * 64 + p) * 2048 + c * 256 + s0 + sg);
      }
    } else {
      const int n0 = (kt - 4) * 64;
#pragma unroll
      for (int k = 0; k < 8; ++k) {
        const int l = lb + 32 * k;
        const float ea = __expf(cas[l]);
        u16x8 raw = *(const u16x8*)(xbf + (long)(c * 256 + l) * CONVD + 4224 + n0 + sg);
        union { u16 u[8]; bf16x8 v; } pk;
#pragma unroll
        for (int u = 0; u < 8; ++u) pk.u[u] = f2bf(ea * bf2f(raw[u]));
        *(bf16x8*)(Ms + l * LDM + sg) = pk.v;
      }
      const float* pT = prevT + (long)(c * 64 + h) * 8192;
#pragma unroll
      for (int half = 0; half < 2; ++half) {
        const int nb = xq * 16 + half * 8;
        union { u16 u[8]; bf16x8 v; } pk;
#pragma unroll
        for (int u = 0; u < 8; ++u) pk.u[u] = f2bf(pT[(n0 + nb + u) * 64 + xp]);
        *(bf16x8*)(Xt + xp * LDM + nb) = pk.v;
      }
    }
    __syncthreads();
#pragma unroll
    for (int ks = 0; ks < 64; ks += 32) {
      bf16x8 af[4], bfv[4];
#pragma unroll
      for (int i = 0; i < 4; ++i)
        af[i] = *(const bf16x8*)(Ms + (w * 64 + i * 16 + fr) * LDM + ks + q * 8);
#pragma unroll
      for (int j = 0; j < 4; ++j)
        bfv[j] = *(const bf16x8*)(Xt + (j * 16 + fr) * LDM + ks + q * 8);
#pragma unroll
      for (int i = 0; i < 4; ++i)
#pragma unroll
        for (int j = 0; j < 4; ++j)
          acc[i][j] = __builtin_amdgcn_mfma_f32_16x16x32_bf16(af[i], bfv[j], acc[i][j], 0, 0, 0);
    }
  }

  const int cr = (lane >> 4) * 4;
  const int cc = lane & 15;
  const float dh = Dp[h];
#pragma unroll
  for (int i = 0; i < 4; ++i)
#pragma unroll
    for (int j = 0; j < 4; ++j) {
      const int p = j * 16 + cc;
#pragma unroll
      for (int t = 0; t < 4; ++t) {
        const int row = w * 64 + i * 16 + cr + t;
        const float xv = bf2f(xbf[(long)(c * 256 + row) * CONVD + h * 64 + p]);
        Y[(long)(c * 256 + row) * 4096 + h * 64 + p] = acc[i][j][t] + dh * xv;
      }
    }
}

// ---------- gated RMSNorm -> bf16 z ----------
__global__ __launch_bounds__(256) void rmsnorm_kernel(const float* __restrict__ Y,
                                                      const float* __restrict__ proj,
                                                      const float* __restrict__ nw,
                                                      u16* __restrict__ zbf) {
  __shared__ float red[256];
  int t = blockIdx.x, tid = threadIdx.x;
  const float* y = Y + (long)t * 4096;
  const float* g = proj + (long)t * LDP;
  float zv[16];
  float s = 0.f;
#pragma unroll
  for (int k = 0; k < 16; ++k) {
    int i = tid + k * 256;
    float gv = g[i];
    float z = y[i] * (gv / (1.f + __expf(-gv)));
    zv[k] = z;
    s += z * z;
  }
  red[tid] = s;
  __syncthreads();
  if (tid < 128) red[tid] += red[tid + 128];
  __syncthreads();
  if (tid < 64) {
    float v = red[tid] + red[tid + 64];
    v += __shfl_down(v, 32);
    v += __shfl_down(v, 16);
    v += __shfl_down(v, 8);
    v += __shfl_down(v, 4);
    v += __shfl_down(v, 2);
    v += __shfl_down(v, 1);
    if (tid == 0) red[0] = v;
  }
  __syncthreads();
  float scale = rsqrtf(red[0] * (1.f / 4096.f) + 1e-5f);
#pragma unroll
  for (int k = 0; k < 16; ++k) {
    int i = tid + k * 256;
    zbf[(long)t * 4096 + i] = f2bf(zv[k] * scale * nw[i]);
  }
}

// ---------- launch ----------
extern "C" void kernel_launch(void* const* d_in, const int* in_sizes, int n_in,
                              void* d_out, int out_size, void* d_ws, size_t ws_size,
                              hipStream_t stream) {
  const float* hidden = (const float*)d_in[0];
  const float* Win    = (const float*)d_in[1];
  const float* convw  = (const float*)d_in[2];
  const float* convb  = (const float*)d_in[3];
  const float* dtb    = (const float*)d_in[4];
  const float* Ap     = (const float*)d_in[5];
  const float* Dp     = (const float*)d_in[6];
  const float* nw     = (const float*)d_in[7];
  const float* Wout   = (const float*)d_in[8];
  float* out = (float*)d_out;
  char* ws = (char*)d_ws;

  // workspace layout (bytes); Y overlays hb+WinT (dead after GEMM1)
  u16*   hb    = (u16*)(ws + 0);            //  8,388,608
  u16*   WinT  = (u16*)(ws + 8388608L);     // 35,127,296  [8576][2048] bf16
  float* proj  = (float*)(ws + 43515904L);  // 70,254,592  [2048][8576] f32
  u16*   WoutT = (u16*)(ws + 113770496L);   // 16,777,216  [2048][4096] bf16
  u16*   xbf   = (u16*)(ws + 130547712L);   // 17,825,792  [2048][4352] bf16
  u16*   xT    = (u16*)(ws + 148373504L);   // 17,301,504  [4224][2048] bf16
  float* dt2   = (float*)(ws + 165675008L); //    524,288  [64][2048]
  float* cA2   = (float*)(ws + 166199296L); //    524,288  [64][2048]
  float* CBv   = (float*)(ws + 166723584L); //  2,097,152  [8][256][256]
  float* stT   = (float*)(ws + 168820736L); // 16,777,216  [8][64][128][64]
  float* prevT = (float*)(ws + 185597952L); // 16,777,216
  u16*   zbf   = (u16*)(ws + 202375168L);   // 16,777,216  [2048][4096] bf16
  float* Y     = (float*)(ws + 0);          // 33,554,432  [2048][4096] f32 (overlay)

  cvt_bf16<<<16384, 256, 0, stream>>>(hidden, hb, 4194304);
  transpose_bf16<<<dim3(268, 64), dim3(32, 8), 0, stream>>>(Win, WinT, 2048, 8512);
  transpose_bf16<<<dim3(64, 128), dim3(32, 8), 0, stream>>>(Wout, WoutT, 4096, 2048);
  gemm_bt<<<dim3(67, 16), 256, 0, stream>>>(hb, WinT, proj, 2048, 8576, 2048);
  conv_silu<<<34816, 256, 0, stream>>>(proj, convw, convb, xbf);
  transpose_u16k<<<dim3(132, 64), dim3(32, 8), 0, stream>>>(xbf, xT);
  dt_cumsum<<<dim3(8, 64), 256, 0, stream>>>(proj, dtb, Ap, dt2, cA2);
  cb_gemm<<<dim3(2, 2, 8), 256, 0, stream>>>(xbf, CBv);
  states_kernel<<<dim3(8, 64), 256, 0, stream>>>(xT, dt2, cA2, stT);
  scan_kernel<<<2048, 256, 0, stream>>>(stT, cA2, prevT);
  ssm_y_kernel<<<dim3(8, 64), 256, 0, stream>>>(xbf, xT, dt2, cA2, CBv, prevT, Dp, Y);
  rmsnorm_kernel<<<2048, 256, 0, stream>>>(Y, proj, nw, zbf);
  gemm_bt<<<dim3(16, 16), 256, 0, stream>>>(zbf, WoutT, out, 2048, 2048, 4096);
}

// Round 4
// 485.396 us; speedup vs baseline: 1.9155x; 1.0404x over previous
//
#include <hip/hip_runtime.h>

// ---------- types ----------
typedef __bf16 bf16_t;
typedef bf16_t bf16x8 __attribute__((ext_vector_type(8)));
typedef float f32x4 __attribute__((ext_vector_type(4)));
typedef unsigned short u16;
typedef u16 u16x8 __attribute__((ext_vector_type(8)));
typedef u16 u16x4 __attribute__((ext_vector_type(4)));

// ---------- model dims ----------
#define SEQ   2048
#define HID   2048
#define INTER 4096
#define NH    64
#define HD    64
#define CONVD 4352
#define DIN   8512
#define LDP   8576L   // proj leading dim, padded to 67*128
#define CHNK  256
#define NC    8

__device__ __forceinline__ u16 f2bf(float f) {
  union { float f; unsigned u; } a; a.f = f;
  return (u16)((a.u + 0x7fffu + ((a.u >> 16) & 1u)) >> 16);
}
__device__ __forceinline__ float bf2f(u16 u) {
  union { unsigned u; float f; } a; a.u = ((unsigned)u) << 16;
  return a.f;
}

__device__ __forceinline__ void gl2lds16(const void* g, void* l) {
  auto gp = reinterpret_cast<__attribute__((address_space(1))) void*>(
      (unsigned long long)g);
  auto lp = reinterpret_cast<__attribute__((address_space(3))) void*>(
      (unsigned)(unsigned long long)l);
  __builtin_amdgcn_global_load_lds(gp, lp, 16, 0, 0);
}

// ---------- fp32 -> bf16 flat convert (vectorized, n4 = n/4) ----------
__global__ __launch_bounds__(256) void cvt_bf16(const float* __restrict__ s,
                                                u16* __restrict__ d, int n4) {
  int i = blockIdx.x * 256 + threadIdx.x;
  if (i < n4) {
    f32x4 v = ((const f32x4*)s)[i];
    u16x4 r;
#pragma unroll
    for (int k = 0; k < 4; ++k) r[k] = f2bf(v[k]);
    ((u16x4*)d)[i] = r;
  }
}

// ---------- transpose + convert: src[R][Cc] fp32 -> dst[n][R] bf16 (zero-pad n>=Cc) ----------
__global__ void transpose_bf16(const float* __restrict__ src, u16* __restrict__ dst,
                               int R, int Cc) {
  __shared__ float t[32][33];
  int n0 = blockIdx.x * 32, k0 = blockIdx.y * 32;
  int tx = threadIdx.x, ty = threadIdx.y;
  for (int i = ty; i < 32; i += 8) {
    int n = n0 + tx;
    t[i][tx] = (n < Cc) ? src[(long)(k0 + i) * Cc + n] : 0.f;
  }
  __syncthreads();
  for (int i = ty; i < 32; i += 8)
    dst[(long)(n0 + i) * R + k0 + tx] = f2bf(t[tx][i]);
}

// ---------- u16 transpose: xbf[2048][4352] cols 0..4223 -> xT[4224][2048] ----------
__global__ void transpose_u16k(const u16* __restrict__ src, u16* __restrict__ dst) {
  __shared__ u16 t[32][34];
  int n0 = blockIdx.x * 32, k0 = blockIdx.y * 32;
  int tx = threadIdx.x, ty = threadIdx.y;
  for (int i = ty; i < 32; i += 8)
    t[i][tx] = src[(long)(k0 + i) * CONVD + n0 + tx];
  __syncthreads();
  for (int i = ty; i < 32; i += 8)
    dst[(long)(n0 + i) * 2048 + k0 + tx] = t[tx][i];
}

// ---------- bf16 MFMA GEMM: C[M,N] = A[M,K]*Bt[N,K]^T, 128x128 tile, BK=32 ----------
// XOR-swizzled LDS: LDS[r][chunk c] holds global chunk c^(r&3)  -> conflict-free frag reads.
// Optional split-K over blockIdx.z: each z does Klen of the lda-strided K, writes C + z*zstride.
__global__ __launch_bounds__(256, 2) void gemm_bt(const u16* __restrict__ A,
                                                  const u16* __restrict__ Bt,
                                                  float* __restrict__ C,
                                                  int M, int N, int lda, int Klen,
                                                  long zstride) {
  __shared__ __align__(16) u16 As[128 * 32];
  __shared__ __align__(16) u16 Bs[128 * 32];
  const int kz = blockIdx.z;
  A  += (long)kz * Klen;
  Bt += (long)kz * Klen;
  C  += (long)kz * zstride;
  const int tid = threadIdx.x;
  const int lane = tid & 63;
  const int w = tid >> 6;
  const int wm = w >> 1, wn = w & 1;
  const long bm = blockIdx.y, bn = blockIdx.x;

  f32x4 acc[4][4];
#pragma unroll
  for (int i = 0; i < 4; ++i)
#pragma unroll
    for (int j = 0; j < 4; ++j) acc[i][j] = (f32x4){0.f, 0.f, 0.f, 0.f};

  const int sr = w * 32 + (lane >> 2);                 // staging row (pass0); pass1 = +16
  const int sc = ((lane & 3) ^ ((lane >> 2) & 3)) * 8; // swizzled source chunk
  const u16* Ag = A + bm * 128 * (long)lda;
  const u16* Bg = Bt + bn * 128 * (long)lda;
  u16* lA0 = As + w * 1024 + lane * 8;
  u16* lA1 = As + w * 1024 + 512 + lane * 8;
  u16* lB0 = Bs + w * 1024 + lane * 8;
  u16* lB1 = Bs + w * 1024 + 512 + lane * 8;
  const int fr = lane & 15, q = lane >> 4;
  const int pc = ((q ^ (fr & 3)) << 3);                // physical chunk offset (elements)

  for (int k0 = 0; k0 < Klen; k0 += 32) {
    __syncthreads();
    const u16* a0 = Ag + (long)sr * lda + k0 + sc;
    const u16* b0 = Bg + (long)sr * lda + k0 + sc;
    gl2lds16(a0, lA0);
    gl2lds16(a0 + 16 * (long)lda, lA1);
    gl2lds16(b0, lB0);
    gl2lds16(b0 + 16 * (long)lda, lB1);
    __builtin_amdgcn_s_waitcnt(0);
    __syncthreads();
    bf16x8 af[4], bfv[4];
#pragma unroll
    for (int i = 0; i < 4; ++i)
      af[i] = *(const bf16x8*)(As + ((wm * 64 + i * 16 + fr) << 5) + pc);
#pragma unroll
    for (int j = 0; j < 4; ++j)
      bfv[j] = *(const bf16x8*)(Bs + ((wn * 64 + j * 16 + fr) << 5) + pc);
#pragma unroll
    for (int i = 0; i < 4; ++i)
#pragma unroll
      for (int j = 0; j < 4; ++j)
        acc[i][j] = __builtin_amdgcn_mfma_f32_16x16x32_bf16(af[i], bfv[j], acc[i][j], 0, 0, 0);
  }
  const int cr = (lane >> 4) * 4;
  const int cc = lane & 15;
#pragma unroll
  for (int i = 0; i < 4; ++i)
#pragma unroll
    for (int j = 0; j < 4; ++j) {
      long r = bm * 128 + wm * 64 + i * 16 + cr;
      long cidx = bn * 128 + wn * 64 + j * 16 + cc;
      float* cp = C + r * (long)N + cidx;
#pragma unroll
      for (int t = 0; t < 4; ++t) cp[(long)t * N] = acc[i][j][t];
    }
}

// ---------- split-K partial add: out = a + b (vector) ----------
__global__ __launch_bounds__(256) void add2_kernel(const float* __restrict__ a,
                                                   const float* __restrict__ b,
                                                   float* __restrict__ o) {
  int i = blockIdx.x * 256 + threadIdx.x;
  ((f32x4*)o)[i] = ((const f32x4*)a)[i] + ((const f32x4*)b)[i];
}

// ---------- depthwise causal conv (K=4) + SiLU -> bf16 xbf ----------
__global__ __launch_bounds__(256) void conv_silu(const float* __restrict__ proj,
                                                 const float* __restrict__ cw,
                                                 const float* __restrict__ cb,
                                                 u16* __restrict__ xbf) {
  int idx = blockIdx.x * 256 + threadIdx.x;   // t*CONVD + c
  int c = idx % CONVD;
  int t = idx / CONVD;
  float acc = cb[c];
#pragma unroll
  for (int k = 0; k < 4; ++k) {
    int tt = t - 3 + k;
    if (tt >= 0) acc += cw[c * 4 + k] * proj[(long)tt * LDP + INTER + c];
  }
  xbf[idx] = f2bf(acc / (1.f + __expf(-acc)));   // SiLU
}

// ---------- dt softplus + per-chunk cumsum (Hillis-Steele), [h][t] layout ----------
__global__ __launch_bounds__(256) void dt_cumsum(const float* __restrict__ proj,
                                                 const float* __restrict__ dtb,
                                                 const float* __restrict__ A,
                                                 float* __restrict__ dt2,
                                                 float* __restrict__ cA2) {
  __shared__ float sc[256];
  int c = blockIdx.x, h = blockIdx.y, l = threadIdx.x;
  float v = proj[(long)(c * 256 + l) * LDP + 8448 + h] + dtb[h];
  float sp = (v > 20.f) ? v : log1pf(__expf(v));
  dt2[h * 2048 + c * 256 + l] = sp;
  sc[l] = sp * A[h];
  __syncthreads();
  for (int off = 1; off < 256; off <<= 1) {
    float t = (l >= off) ? sc[l - off] : 0.f;
    __syncthreads();
    sc[l] += t;
    __syncthreads();
  }
  cA2[h * 2048 + c * 256 + l] = sc[l];
}

// ---------- CB[c][l][s] = C[l,:].B[s,:] via MFMA, per-chunk strided GEMM (swizzled LDS) ----------
__global__ __launch_bounds__(256, 2) void cb_gemm(const u16* __restrict__ xbf,
                                                  float* __restrict__ CB) {
  __shared__ __align__(16) u16 As[128 * 32];
  __shared__ __align__(16) u16 Bs[128 * 32];
  const int tid = threadIdx.x;
  const int lane = tid & 63;
  const int w = tid >> 6;
  const int wm = w >> 1, wn = w & 1;
  const int bm = blockIdx.y, bn = blockIdx.x, c = blockIdx.z;

  f32x4 acc[4][4];
#pragma unroll
  for (int i = 0; i < 4; ++i)
#pragma unroll
    for (int j = 0; j < 4; ++j) acc[i][j] = (f32x4){0.f, 0.f, 0.f, 0.f};

  const int sr = w * 32 + (lane >> 2);
  const int sc = ((lane & 3) ^ ((lane >> 2) & 3)) * 8;
  const u16* Ag = xbf + (long)(c * 256 + bm * 128) * CONVD + 4224;  // C region
  const u16* Bg = xbf + (long)(c * 256 + bn * 128) * CONVD + 4096;  // B region
  u16* lA0 = As + w * 1024 + lane * 8;
  u16* lA1 = As + w * 1024 + 512 + lane * 8;
  u16* lB0 = Bs + w * 1024 + lane * 8;
  u16* lB1 = Bs + w * 1024 + 512 + lane * 8;
  const int fr = lane & 15, q = lane >> 4;
  const int pc = ((q ^ (fr & 3)) << 3);

  for (int k0 = 0; k0 < 128; k0 += 32) {
    __syncthreads();
    const u16* a0 = Ag + (long)sr * CONVD + k0 + sc;
    const u16* b0 = Bg + (long)sr * CONVD + k0 + sc;
    gl2lds16(a0, lA0);
    gl2lds16(a0 + 16L * CONVD, lA1);
    gl2lds16(b0, lB0);
    gl2lds16(b0 + 16L * CONVD, lB1);
    __builtin_amdgcn_s_waitcnt(0);
    __syncthreads();
    bf16x8 af[4], bfv[4];
#pragma unroll
    for (int i = 0; i < 4; ++i)
      af[i] = *(const bf16x8*)(As + ((wm * 64 + i * 16 + fr) << 5) + pc);
#pragma unroll
    for (int j = 0; j < 4; ++j)
      bfv[j] = *(const bf16x8*)(Bs + ((wn * 64 + j * 16 + fr) << 5) + pc);
#pragma unroll
    for (int i = 0; i < 4; ++i)
#pragma unroll
      for (int j = 0; j < 4; ++j)
        acc[i][j] = __builtin_amdgcn_mfma_f32_16x16x32_bf16(af[i], bfv[j], acc[i][j], 0, 0, 0);
  }
  const int cr = (lane >> 4) * 4;
  const int cc = lane & 15;
  float* Cc = CB + (long)c * 65536;
#pragma unroll
  for (int i = 0; i < 4; ++i)
#pragma unroll
    for (int j = 0; j < 4; ++j) {
      int r = bm * 128 + wm * 64 + i * 16 + cr;
      int cidx = bn * 128 + wn * 64 + j * 16 + cc;
      float* cp = Cc + (long)r * 256 + cidx;
#pragma unroll
      for (int t = 0; t < 4; ++t) cp[t * 256] = acc[i][j][t];
    }
}

// ---------- states via MFMA: stT[n][p] = sum_l (B[l][n]*wl[l]) * x[l][p] ----------
#define LDM 72
__global__ __launch_bounds__(256) void states_kernel(const u16* __restrict__ xT,
                                                     const float* __restrict__ dt2,
                                                     const float* __restrict__ cA2,
                                                     float* __restrict__ stT) {
  __shared__ __align__(16) u16 Ms[128 * LDM];  // Bw [n][l_local]
  __shared__ __align__(16) u16 Xs[64 * LDM];   // x  [p][l_local]
  __shared__ float wl[256];
  const int c = blockIdx.x, h = blockIdx.y;
  const int tid = threadIdx.x;
  const int lane = tid & 63, w = tid >> 6;
  const int fr = lane & 15, q = lane >> 4;
  {
    float calast = cA2[h * 2048 + c * 256 + 255];
    float ca = cA2[h * 2048 + c * 256 + tid];
    wl[tid] = __expf(calast - ca) * dt2[h * 2048 + c * 256 + tid];
  }
  f32x4 acc[2][4];
#pragma unroll
  for (int i = 0; i < 2; ++i)
#pragma unroll
    for (int j = 0; j < 4; ++j) acc[i][j] = (f32x4){0.f, 0.f, 0.f, 0.f};

  const int lc8 = (tid & 7) * 8;
  const int rn = tid >> 3;   // 0..31
  __syncthreads();

  for (int kt = 0; kt < 4; ++kt) {
    __syncthreads();
#pragma unroll
    for (int r = 0; r < 4; ++r) {
      int n = rn + 32 * r;
      u16x8 raw = *(const u16x8*)(xT + (long)(4096 + n) * 2048 + c * 256 + kt * 64 + lc8);
      union { u16 u[8]; bf16x8 v; } pk;
#pragma unroll
      for (int u = 0; u < 8; ++u)
        pk.u[u] = f2bf(bf2f(raw[u]) * wl[kt * 64 + lc8 + u]);
      *(bf16x8*)(Ms + n * LDM + lc8) = pk.v;
    }
#pragma unroll
    for (int r = 0; r < 2; ++r) {
      int p = rn + 32 * r;
      *(bf16x8*)(Xs + p * LDM + lc8) =
          *(const bf16x8*)(xT + (long)(h * 64 + p) * 2048 + c * 256 + kt * 64 + lc8);
    }
    __syncthreads();
#pragma unroll
    for (int ks = 0; ks < 64; ks += 32) {
      bf16x8 af[2], xf[4];
#pragma unroll
      for (int i = 0; i < 2; ++i)
        af[i] = *(const bf16x8*)(Ms + (w * 32 + i * 16 + fr) * LDM + ks + q * 8);
#pragma unroll
      for (int j = 0; j < 4; ++j)
        xf[j] = *(const bf16x8*)(Xs + (j * 16 + fr) * LDM + ks + q * 8);
#pragma unroll
      for (int i = 0; i < 2; ++i)
#pragma unroll
        for (int j = 0; j < 4; ++j)
          acc[i][j] = __builtin_amdgcn_mfma_f32_16x16x32_bf16(af[i], xf[j], acc[i][j], 0, 0, 0);
    }
  }
  const int cr = (lane >> 4) * 4;
  const int cc = lane & 15;
  float* outp = stT + (long)(c * 64 + h) * 8192;
#pragma unroll
  for (int i = 0; i < 2; ++i)
#pragma unroll
    for (int j = 0; j < 4; ++j) {
      int n = w * 32 + i * 16 + cr;
      int p = j * 16 + cc;
#pragma unroll
      for (int t = 0; t < 4; ++t) outp[(n + t) * 64 + p] = acc[i][j][t];
    }
}

// ---------- 8-chunk inter-chunk scan ----------
__global__ __launch_bounds__(256) void scan_kernel(const float* __restrict__ stT,
                                                   const float* __restrict__ cA2,
                                                   float* __restrict__ prevT) {
  int id = blockIdx.x * 256 + threadIdx.x;   // h*8192 + n*64 + p
  int h = id >> 13;
  float acc = 0.f;
#pragma unroll
  for (int c = 0; c < NC; ++c) {
    prevT[(long)c * 524288 + id] = acc;
    float cd = __expf(cA2[h * 2048 + c * 256 + 255]);
    acc = acc * cd + stT[(long)c * 524288 + id];
  }
}

// ---------- intra+inter SSM output via bf16 MFMA: Y[256x64] = M[256x384] @ X[384x64] ----------
__global__ __launch_bounds__(256) void ssm_y_kernel(const u16* __restrict__ xbf,
                                                    const u16* __restrict__ xT,
                                                    const float* __restrict__ dt2,
                                                    const float* __restrict__ cA2,
                                                    const float* __restrict__ CB,
                                                    const float* __restrict__ prevT,
                                                    const float* __restrict__ Dp,
                                                    float* __restrict__ Y) {
  __shared__ __align__(16) u16 Ms[256 * LDM];
  __shared__ __align__(16) u16 Xt[64 * LDM];
  __shared__ float cas[256];
  __shared__ float dts[256];
  const int c = blockIdx.x, h = blockIdx.y;
  const int tid = threadIdx.x;
  const int lane = tid & 63;
  const int w = tid >> 6;
  const int fr = lane & 15, q = lane >> 4;

  cas[tid] = cA2[h * 2048 + c * 256 + tid];
  dts[tid] = dt2[h * 2048 + c * 256 + tid];

  f32x4 acc[4][4];
#pragma unroll
  for (int i = 0; i < 4; ++i)
#pragma unroll
    for (int j = 0; j < 4; ++j) acc[i][j] = (f32x4){0.f, 0.f, 0.f, 0.f};

  const int sg = (tid & 7) * 8;
  const int lb = tid >> 3;
  const int xp = tid & 63;
  const int xq = tid >> 6;

  __syncthreads();

  for (int kt = 0; kt < 6; ++kt) {
    __syncthreads();
    if (kt < 4) {
      const int s0 = kt * 64;
      f32x4 e0 = *(const f32x4*)&cas[s0 + sg];
      f32x4 e1 = *(const f32x4*)&cas[s0 + sg + 4];
      f32x4 d0 = *(const f32x4*)&dts[s0 + sg];
      f32x4 d1 = *(const f32x4*)&dts[s0 + sg + 4];
#pragma unroll
      for (int k = 0; k < 8; ++k) {
        const int l = lb + 32 * k;
        const float cal = cas[l];
        const float* cb = CB + (long)c * 65536 + (long)l * 256 + s0 + sg;
        f32x4 c0 = *(const f32x4*)cb;
        f32x4 c1 = *(const f32x4*)(cb + 4);
        union { u16 u[8]; bf16x8 v; } pk;
#pragma unroll
        for (int u = 0; u < 8; ++u) {
          int s = s0 + sg + u;
          float cv = (u < 4) ? c0[u] : c1[u - 4];
          float cs = (u < 4) ? e0[u] : e1[u - 4];
          float dv = (u < 4) ? d0[u] : d1[u - 4];
          float m = (s <= l) ? cv * __expf(cal - cs) * dv : 0.f;
          pk.u[u] = f2bf(m);
        }
        *(bf16x8*)(Ms + l * LDM + sg) = pk.v;
      }
#pragma unroll
      for (int r = 0; r < 2; ++r) {
        int p = (tid >> 3) + 32 * r;
        *(bf16x8*)(Xt + p * LDM + sg) =
            *(const bf16x8*)(xT + (long)(h * 64 + p) * 2048 + c * 256 + s0 + sg);
      }
    } else {
      const int n0 = (kt - 4) * 64;
#pragma unroll
      for (int k = 0; k < 8; ++k) {
        const int l = lb + 32 * k;
        const float ea = __expf(cas[l]);
        u16x8 raw = *(const u16x8*)(xbf + (long)(c * 256 + l) * CONVD + 4224 + n0 + sg);
        union { u16 u[8]; bf16x8 v; } pk;
#pragma unroll
        for (int u = 0; u < 8; ++u) pk.u[u] = f2bf(ea * bf2f(raw[u]));
        *(bf16x8*)(Ms + l * LDM + sg) = pk.v;
      }
      const float* pT = prevT + (long)(c * 64 + h) * 8192;
#pragma unroll
      for (int half = 0; half < 2; ++half) {
        const int nb = xq * 16 + half * 8;
        union { u16 u[8]; bf16x8 v; } pk;
#pragma unroll
        for (int u = 0; u < 8; ++u) pk.u[u] = f2bf(pT[(n0 + nb + u) * 64 + xp]);
        *(bf16x8*)(Xt + xp * LDM + nb) = pk.v;
      }
    }
    __syncthreads();
#pragma unroll
    for (int ks = 0; ks < 64; ks += 32) {
      bf16x8 af[4], bfv[4];
#pragma unroll
      for (int i = 0; i < 4; ++i)
        af[i] = *(const bf16x8*)(Ms + (w * 64 + i * 16 + fr) * LDM + ks + q * 8);
#pragma unroll
      for (int j = 0; j < 4; ++j)
        bfv[j] = *(const bf16x8*)(Xt + (j * 16 + fr) * LDM + ks + q * 8);
#pragma unroll
      for (int i = 0; i < 4; ++i)
#pragma unroll
        for (int j = 0; j < 4; ++j)
          acc[i][j] = __builtin_amdgcn_mfma_f32_16x16x32_bf16(af[i], bfv[j], acc[i][j], 0, 0, 0);
    }
  }

  const int cr = (lane >> 4) * 4;
  const int cc = lane & 15;
  const float dh = Dp[h];
#pragma unroll
  for (int i = 0; i < 4; ++i)
#pragma unroll
    for (int j = 0; j < 4; ++j) {
      const int p = j * 16 + cc;
#pragma unroll
      for (int t = 0; t < 4; ++t) {
        const int row = w * 64 + i * 16 + cr + t;
        const float xv = bf2f(xbf[(long)(c * 256 + row) * CONVD + h * 64 + p]);
        Y[(long)(c * 256 + row) * 4096 + h * 64 + p] = acc[i][j][t] + dh * xv;
      }
    }
}

// ---------- gated RMSNorm -> bf16 z ----------
__global__ __launch_bounds__(256) void rmsnorm_kernel(const float* __restrict__ Y,
                                                      const float* __restrict__ proj,
                                                      const float* __restrict__ nw,
                                                      u16* __restrict__ zbf) {
  __shared__ float red[256];
  int t = blockIdx.x, tid = threadIdx.x;
  const float* y = Y + (long)t * 4096;
  const float* g = proj + (long)t * LDP;
  float zv[16];
  float s = 0.f;
#pragma unroll
  for (int k = 0; k < 16; ++k) {
    int i = tid + k * 256;
    float gv = g[i];
    float z = y[i] * (gv / (1.f + __expf(-gv)));
    zv[k] = z;
    s += z * z;
  }
  red[tid] = s;
  __syncthreads();
  if (tid < 128) red[tid] += red[tid + 128];
  __syncthreads();
  if (tid < 64) {
    float v = red[tid] + red[tid + 64];
    v += __shfl_down(v, 32);
    v += __shfl_down(v, 16);
    v += __shfl_down(v, 8);
    v += __shfl_down(v, 4);
    v += __shfl_down(v, 2);
    v += __shfl_down(v, 1);
    if (tid == 0) red[0] = v;
  }
  __syncthreads();
  float scale = rsqrtf(red[0] * (1.f / 4096.f) + 1e-5f);
#pragma unroll
  for (int k = 0; k < 16; ++k) {
    int i = tid + k * 256;
    zbf[(long)t * 4096 + i] = f2bf(zv[k] * scale * nw[i]);
  }
}

// ---------- launch ----------
extern "C" void kernel_launch(void* const* d_in, const int* in_sizes, int n_in,
                              void* d_out, int out_size, void* d_ws, size_t ws_size,
                              hipStream_t stream) {
  const float* hidden = (const float*)d_in[0];
  const float* Win    = (const float*)d_in[1];
  const float* convw  = (const float*)d_in[2];
  const float* convb  = (const float*)d_in[3];
  const float* dtb    = (const float*)d_in[4];
  const float* Ap     = (const float*)d_in[5];
  const float* Dp     = (const float*)d_in[6];
  const float* nw     = (const float*)d_in[7];
  const float* Wout   = (const float*)d_in[8];
  float* out = (float*)d_out;
  char* ws = (char*)d_ws;

  // workspace layout (bytes); Y overlays hb+WinT; GEMM2 partials overlay proj
  u16*   hb    = (u16*)(ws + 0);            //  8,388,608
  u16*   WinT  = (u16*)(ws + 8388608L);     // 35,127,296  [8576][2048] bf16
  float* proj  = (float*)(ws + 43515904L);  // 70,254,592  [2048][8576] f32
  u16*   WoutT = (u16*)(ws + 113770496L);   // 16,777,216  [2048][4096] bf16
  u16*   xbf   = (u16*)(ws + 130547712L);   // 17,825,792  [2048][4352] bf16
  u16*   xT    = (u16*)(ws + 148373504L);   // 17,301,504  [4224][2048] bf16
  float* dt2   = (float*)(ws + 165675008L); //    524,288  [64][2048]
  float* cA2   = (float*)(ws + 166199296L); //    524,288  [64][2048]
  float* CBv   = (float*)(ws + 166723584L); //  2,097,152  [8][256][256]
  float* stT   = (float*)(ws + 168820736L); // 16,777,216  [8][64][128][64]
  float* prevT = (float*)(ws + 185597952L); // 16,777,216
  u16*   zbf   = (u16*)(ws + 202375168L);   // 16,777,216  [2048][4096] bf16
  float* Y     = (float*)(ws + 0);          // 33,554,432  [2048][4096] f32 (overlay)
  float* Cp    = (float*)(ws + 43515904L);  // 33,554,432  GEMM2 partials (overlay proj)

  cvt_bf16<<<4096, 256, 0, stream>>>(hidden, hb, 1048576);
  transpose_bf16<<<dim3(268, 64), dim3(32, 8), 0, stream>>>(Win, WinT, 2048, 8512);
  transpose_bf16<<<dim3(64, 128), dim3(32, 8), 0, stream>>>(Wout, WoutT, 4096, 2048);
  gemm_bt<<<dim3(67, 16, 1), 256, 0, stream>>>(hb, WinT, proj, 2048, 8576, 2048, 2048, 0L);
  conv_silu<<<34816, 256, 0, stream>>>(proj, convw, convb, xbf);
  transpose_u16k<<<dim3(132, 64), dim3(32, 8), 0, stream>>>(xbf, xT);
  dt_cumsum<<<dim3(8, 64), 256, 0, stream>>>(proj, dtb, Ap, dt2, cA2);
  cb_gemm<<<dim3(2, 2, 8), 256, 0, stream>>>(xbf, CBv);
  states_kernel<<<dim3(8, 64), 256, 0, stream>>>(xT, dt2, cA2, stT);
  scan_kernel<<<2048, 256, 0, stream>>>(stT, cA2, prevT);
  ssm_y_kernel<<<dim3(8, 64), 256, 0, stream>>>(xbf, xT, dt2, cA2, CBv, prevT, Dp, Y);
  rmsnorm_kernel<<<2048, 256, 0, stream>>>(Y, proj, nw, zbf);
  gemm_bt<<<dim3(16, 16, 2), 256, 0, stream>>>(zbf, WoutT, Cp, 2048, 2048, 4096, 2048, 4194304L);
  add2_kernel<<<4096, 256, 0, stream>>>(Cp, Cp + 4194304, out);
}

// Round 5
// 415.151 us; speedup vs baseline: 2.2396x; 1.1692x over previous
//
#include <hip/hip_runtime.h>

// ---------- types ----------
typedef __bf16 bf16_t;
typedef bf16_t bf16x8 __attribute__((ext_vector_type(8)));
typedef float f32x4 __attribute__((ext_vector_type(4)));
typedef unsigned short u16;
typedef u16 u16x8 __attribute__((ext_vector_type(8)));
typedef u16 u16x4 __attribute__((ext_vector_type(4)));

// ---------- model dims ----------
#define SEQ   2048
#define HID   2048
#define INTER 4096
#define NH    64
#define HD    64
#define CONVD 4352
#define DIN   8512
#define LDP   8576L   // proj leading dim, padded to 67*128
#define CHNK  256
#define NC    8

__device__ __forceinline__ u16 f2bf(float f) {
  union { float f; unsigned u; } a; a.f = f;
  return (u16)((a.u + 0x7fffu + ((a.u >> 16) & 1u)) >> 16);
}
__device__ __forceinline__ float bf2f(u16 u) {
  union { unsigned u; float f; } a; a.u = ((unsigned)u) << 16;
  return a.f;
}

__device__ __forceinline__ void gl2lds16(const void* g, void* l) {
  auto gp = reinterpret_cast<__attribute__((address_space(1))) void*>(
      (unsigned long long)g);
  auto lp = reinterpret_cast<__attribute__((address_space(3))) void*>(
      (unsigned)(unsigned long long)l);
  __builtin_amdgcn_global_load_lds(gp, lp, 16, 0, 0);
}

// ---------- fp32 -> bf16 flat convert (vectorized, n4 = n/4) ----------
__global__ __launch_bounds__(256) void cvt_bf16(const float* __restrict__ s,
                                                u16* __restrict__ d, int n4) {
  int i = blockIdx.x * 256 + threadIdx.x;
  if (i < n4) {
    f32x4 v = ((const f32x4*)s)[i];
    u16x4 r;
#pragma unroll
    for (int k = 0; k < 4; ++k) r[k] = f2bf(v[k]);
    ((u16x4*)d)[i] = r;
  }
}

// ---------- transpose + convert: src[R][Cc] fp32 -> dst[n][R] bf16 (zero-pad n>=Cc) ----------
__global__ void transpose_bf16(const float* __restrict__ src, u16* __restrict__ dst,
                               int R, int Cc) {
  __shared__ float t[32][33];
  int n0 = blockIdx.x * 32, k0 = blockIdx.y * 32;
  int tx = threadIdx.x, ty = threadIdx.y;
  for (int i = ty; i < 32; i += 8) {
    int n = n0 + tx;
    t[i][tx] = (n < Cc) ? src[(long)(k0 + i) * Cc + n] : 0.f;
  }
  __syncthreads();
  for (int i = ty; i < 32; i += 8)
    dst[(long)(n0 + i) * R + k0 + tx] = f2bf(t[tx][i]);
}

// ---------- bf16 MFMA GEMM: C[2048,N] = A * Bt^T, 128x128 tile, BK=64 ----------
// XOR-8 swizzled LDS rows; XCD-contiguous block remap (assumes 16 row-tiles, nb%8==0).
__global__ __launch_bounds__(256, 2) void gemm_bt(const u16* __restrict__ A,
                                                  const u16* __restrict__ Bt,
                                                  float* __restrict__ C,
                                                  int N, int lda, int Klen,
                                                  long zstride) {
  __shared__ __align__(16) u16 As[128 * 64];
  __shared__ __align__(16) u16 Bs[128 * 64];
  const int kz = blockIdx.z;
  A  += (long)kz * Klen;
  Bt += (long)kz * Klen;
  C  += (long)kz * zstride;
  // XCD-contiguous remap: each XCD (id%8) owns a contiguous strip of bn-tiles.
  const int nb = gridDim.x * gridDim.y;
  const int id = blockIdx.x + gridDim.x * blockIdx.y;
  const int s = (id & 7) * (nb >> 3) + (id >> 3);
  const long bm = s & 15;
  const long bn = s >> 4;

  const int tid = threadIdx.x;
  const int lane = tid & 63;
  const int w = tid >> 6;
  const int wm = w >> 1, wn = w & 1;

  f32x4 acc[4][4];
#pragma unroll
  for (int i = 0; i < 4; ++i)
#pragma unroll
    for (int j = 0; j < 4; ++j) acc[i][j] = (f32x4){0.f, 0.f, 0.f, 0.f};

  const int srr = lane >> 3;                 // sub-row 0..7
  const int sc8 = ((lane & 7) ^ srr) * 8;    // swizzled source chunk (elements)
  const u16* Agw = A + (bm * 128 + w * 8 + srr) * (long)lda + sc8;
  const u16* Bgw = Bt + (bn * 128 + w * 8 + srr) * (long)lda + sc8;
  u16* ldA = As + w * 512 + lane * 8;
  u16* ldB = Bs + w * 512 + lane * 8;
  const int fr = lane & 15, q = lane >> 4;
  const int fx = (fr & 7) << 3;

  for (int k0 = 0; k0 < Klen; k0 += 64) {
    __syncthreads();
#pragma unroll
    for (int t = 0; t < 4; ++t) {
      gl2lds16(Agw + k0 + (long)t * 32 * lda, ldA + t * 2048);
      gl2lds16(Bgw + k0 + (long)t * 32 * lda, ldB + t * 2048);
    }
    __builtin_amdgcn_s_waitcnt(0);
    __syncthreads();
#pragma unroll
    for (int ks = 0; ks < 2; ++ks) {
      bf16x8 af[4], bfv[4];
#pragma unroll
      for (int i = 0; i < 4; ++i)
        af[i] = *(const bf16x8*)(As + ((wm * 64 + i * 16 + fr) << 6) +
                                 ((((ks << 2) + q) << 3) ^ fx));
#pragma unroll
      for (int j = 0; j < 4; ++j)
        bfv[j] = *(const bf16x8*)(Bs + ((wn * 64 + j * 16 + fr) << 6) +
                                  ((((ks << 2) + q) << 3) ^ fx));
#pragma unroll
      for (int i = 0; i < 4; ++i)
#pragma unroll
        for (int j = 0; j < 4; ++j)
          acc[i][j] = __builtin_amdgcn_mfma_f32_16x16x32_bf16(af[i], bfv[j], acc[i][j], 0, 0, 0);
    }
  }
  const int cr = (lane >> 4) * 4;
  const int cc = lane & 15;
#pragma unroll
  for (int i = 0; i < 4; ++i)
#pragma unroll
    for (int j = 0; j < 4; ++j) {
      long r = bm * 128 + wm * 64 + i * 16 + cr;
      long cidx = bn * 128 + wn * 64 + j * 16 + cc;
      float* cp = C + r * (long)N + cidx;
#pragma unroll
      for (int t = 0; t < 4; ++t) cp[(long)t * N] = acc[i][j][t];
    }
}

// ---------- split-K partial add: out = a + b (vector) ----------
__global__ __launch_bounds__(256) void add2_kernel(const float* __restrict__ a,
                                                   const float* __restrict__ b,
                                                   float* __restrict__ o) {
  int i = blockIdx.x * 256 + threadIdx.x;
  ((f32x4*)o)[i] = ((const f32x4*)a)[i] + ((const f32x4*)b)[i];
}

// ---------- fused depthwise conv (K=4) + SiLU -> xbf AND xT (transposed) ----------
__global__ __launch_bounds__(256) void conv_silu_t(const float* __restrict__ proj,
                                                   const float* __restrict__ cw,
                                                   const float* __restrict__ cb,
                                                   u16* __restrict__ xbf,
                                                   u16* __restrict__ xT) {
  __shared__ float ld[35][33];
  __shared__ u16 tt[32][34];
  const int c0 = blockIdx.x * 32, t0 = blockIdx.y * 32;
  const int tx = threadIdx.x & 31, ty = threadIdx.x >> 5;
  for (int i = ty; i < 35; i += 8) {
    int t = t0 - 3 + i;
    ld[i][tx] = (t >= 0) ? proj[(long)t * LDP + INTER + c0 + tx] : 0.f;
  }
  const int c = c0 + tx;
  const float w0 = cw[c * 4 + 0], w1 = cw[c * 4 + 1], w2 = cw[c * 4 + 2],
              w3 = cw[c * 4 + 3], bias = cb[c];
  __syncthreads();
  for (int i = ty; i < 32; i += 8) {
    float a = bias + w0 * ld[i][tx] + w1 * ld[i + 1][tx] + w2 * ld[i + 2][tx] +
              w3 * ld[i + 3][tx];
    u16 v = f2bf(a / (1.f + __expf(-a)));
    xbf[(long)(t0 + i) * CONVD + c] = v;
    tt[i][tx] = v;
  }
  __syncthreads();
  if (c0 < 4224) {   // x + B + C regions get transposed
    for (int i = ty; i < 32; i += 8)
      xT[(long)(c0 + i) * 2048 + t0 + tx] = tt[tx][i];
  }
}

// ---------- dt softplus + per-chunk cumsum (Hillis-Steele), [h][t] layout ----------
__global__ __launch_bounds__(256) void dt_cumsum(const float* __restrict__ proj,
                                                 const float* __restrict__ dtb,
                                                 const float* __restrict__ A,
                                                 float* __restrict__ dt2,
                                                 float* __restrict__ cA2) {
  __shared__ float sc[256];
  int c = blockIdx.x, h = blockIdx.y, l = threadIdx.x;
  float v = proj[(long)(c * 256 + l) * LDP + 8448 + h] + dtb[h];
  float sp = (v > 20.f) ? v : log1pf(__expf(v));
  dt2[h * 2048 + c * 256 + l] = sp;
  sc[l] = sp * A[h];
  __syncthreads();
  for (int off = 1; off < 256; off <<= 1) {
    float t = (l >= off) ? sc[l - off] : 0.f;
    __syncthreads();
    sc[l] += t;
    __syncthreads();
  }
  cA2[h * 2048 + c * 256 + l] = sc[l];
}

// ---------- CB[c][l][s] = C[l,:].B[s,:] via MFMA, per-chunk strided GEMM ----------
__global__ __launch_bounds__(256, 2) void cb_gemm(const u16* __restrict__ xbf,
                                                  float* __restrict__ CB) {
  __shared__ __align__(16) u16 As[128 * 32];
  __shared__ __align__(16) u16 Bs[128 * 32];
  const int tid = threadIdx.x;
  const int lane = tid & 63;
  const int w = tid >> 6;
  const int wm = w >> 1, wn = w & 1;
  const int bm = blockIdx.y, bn = blockIdx.x, c = blockIdx.z;

  f32x4 acc[4][4];
#pragma unroll
  for (int i = 0; i < 4; ++i)
#pragma unroll
    for (int j = 0; j < 4; ++j) acc[i][j] = (f32x4){0.f, 0.f, 0.f, 0.f};

  const int sr = w * 32 + (lane >> 2);
  const int sc = ((lane & 3) ^ ((lane >> 2) & 3)) * 8;
  const u16* Ag = xbf + (long)(c * 256 + bm * 128) * CONVD + 4224;  // C region
  const u16* Bg = xbf + (long)(c * 256 + bn * 128) * CONVD + 4096;  // B region
  u16* lA0 = As + w * 1024 + lane * 8;
  u16* lA1 = As + w * 1024 + 512 + lane * 8;
  u16* lB0 = Bs + w * 1024 + lane * 8;
  u16* lB1 = Bs + w * 1024 + 512 + lane * 8;
  const int fr = lane & 15, q = lane >> 4;
  const int pc = ((q ^ (fr & 3)) << 3);

  for (int k0 = 0; k0 < 128; k0 += 32) {
    __syncthreads();
    const u16* a0 = Ag + (long)sr * CONVD + k0 + sc;
    const u16* b0 = Bg + (long)sr * CONVD + k0 + sc;
    gl2lds16(a0, lA0);
    gl2lds16(a0 + 16L * CONVD, lA1);
    gl2lds16(b0, lB0);
    gl2lds16(b0 + 16L * CONVD, lB1);
    __builtin_amdgcn_s_waitcnt(0);
    __syncthreads();
    bf16x8 af[4], bfv[4];
#pragma unroll
    for (int i = 0; i < 4; ++i)
      af[i] = *(const bf16x8*)(As + ((wm * 64 + i * 16 + fr) << 5) + pc);
#pragma unroll
    for (int j = 0; j < 4; ++j)
      bfv[j] = *(const bf16x8*)(Bs + ((wn * 64 + j * 16 + fr) << 5) + pc);
#pragma unroll
    for (int i = 0; i < 4; ++i)
#pragma unroll
      for (int j = 0; j < 4; ++j)
        acc[i][j] = __builtin_amdgcn_mfma_f32_16x16x32_bf16(af[i], bfv[j], acc[i][j], 0, 0, 0);
  }
  const int cr = (lane >> 4) * 4;
  const int cc = lane & 15;
  float* Cc = CB + (long)c * 65536;
#pragma unroll
  for (int i = 0; i < 4; ++i)
#pragma unroll
    for (int j = 0; j < 4; ++j) {
      int r = bm * 128 + wm * 64 + i * 16 + cr;
      int cidx = bn * 128 + wn * 64 + j * 16 + cc;
      float* cp = Cc + (long)r * 256 + cidx;
#pragma unroll
      for (int t = 0; t < 4; ++t) cp[t * 256] = acc[i][j][t];
    }
}

// ---------- states via MFMA: stT[n][p] = sum_l (B[l][n]*wl[l]) * x[l][p] ----------
#define LDM 72
__global__ __launch_bounds__(256) void states_kernel(const u16* __restrict__ xT,
                                                     const float* __restrict__ dt2,
                                                     const float* __restrict__ cA2,
                                                     float* __restrict__ stT) {
  __shared__ __align__(16) u16 Ms[128 * LDM];  // Bw [n][l_local]
  __shared__ __align__(16) u16 Xs[64 * LDM];   // x  [p][l_local]
  __shared__ float wl[256];
  const int c = blockIdx.x, h = blockIdx.y;
  const int tid = threadIdx.x;
  const int lane = tid & 63, w = tid >> 6;
  const int fr = lane & 15, q = lane >> 4;
  {
    float calast = cA2[h * 2048 + c * 256 + 255];
    float ca = cA2[h * 2048 + c * 256 + tid];
    wl[tid] = __expf(calast - ca) * dt2[h * 2048 + c * 256 + tid];
  }
  f32x4 acc[2][4];
#pragma unroll
  for (int i = 0; i < 2; ++i)
#pragma unroll
    for (int j = 0; j < 4; ++j) acc[i][j] = (f32x4){0.f, 0.f, 0.f, 0.f};

  const int lc8 = (tid & 7) * 8;
  const int rn = tid >> 3;   // 0..31
  __syncthreads();

  for (int kt = 0; kt < 4; ++kt) {
    __syncthreads();
#pragma unroll
    for (int r = 0; r < 4; ++r) {
      int n = rn + 32 * r;
      u16x8 raw = *(const u16x8*)(xT + (long)(4096 + n) * 2048 + c * 256 + kt * 64 + lc8);
      union { u16 u[8]; bf16x8 v; } pk;
#pragma unroll
      for (int u = 0; u < 8; ++u)
        pk.u[u] = f2bf(bf2f(raw[u]) * wl[kt * 64 + lc8 + u]);
      *(bf16x8*)(Ms + n * LDM + lc8) = pk.v;
    }
#pragma unroll
    for (int r = 0; r < 2; ++r) {
      int p = rn + 32 * r;
      *(bf16x8*)(Xs + p * LDM + lc8) =
          *(const bf16x8*)(xT + (long)(h * 64 + p) * 2048 + c * 256 + kt * 64 + lc8);
    }
    __syncthreads();
#pragma unroll
    for (int ks = 0; ks < 64; ks += 32) {
      bf16x8 af[2], xf[4];
#pragma unroll
      for (int i = 0; i < 2; ++i)
        af[i] = *(const bf16x8*)(Ms + (w * 32 + i * 16 + fr) * LDM + ks + q * 8);
#pragma unroll
      for (int j = 0; j < 4; ++j)
        xf[j] = *(const bf16x8*)(Xs + (j * 16 + fr) * LDM + ks + q * 8);
#pragma unroll
      for (int i = 0; i < 2; ++i)
#pragma unroll
        for (int j = 0; j < 4; ++j)
          acc[i][j] = __builtin_amdgcn_mfma_f32_16x16x32_bf16(af[i], xf[j], acc[i][j], 0, 0, 0);
    }
  }
  const int cr = (lane >> 4) * 4;
  const int cc = lane & 15;
  float* outp = stT + (long)(c * 64 + h) * 8192;
#pragma unroll
  for (int i = 0; i < 2; ++i)
#pragma unroll
    for (int j = 0; j < 4; ++j) {
      int n = w * 32 + i * 16 + cr;
      int p = j * 16 + cc;
#pragma unroll
      for (int t = 0; t < 4; ++t) outp[(n + t) * 64 + p] = acc[i][j][t];
    }
}

// ---------- 8-chunk inter-chunk scan ----------
__global__ __launch_bounds__(256) void scan_kernel(const float* __restrict__ stT,
                                                   const float* __restrict__ cA2,
                                                   float* __restrict__ prevT) {
  int id = blockIdx.x * 256 + threadIdx.x;   // h*8192 + n*64 + p
  int h = id >> 13;
  float acc = 0.f;
#pragma unroll
  for (int c = 0; c < NC; ++c) {
    prevT[(long)c * 524288 + id] = acc;
    float cd = __expf(cA2[h * 2048 + c * 256 + 255]);
    acc = acc * cd + stT[(long)c * 524288 + id];
  }
}

// ---------- intra+inter SSM output via bf16 MFMA: Y[256x64] = M[256x384] @ X[384x64] ----------
__global__ __launch_bounds__(256) void ssm_y_kernel(const u16* __restrict__ xbf,
                                                    const u16* __restrict__ xT,
                                                    const float* __restrict__ dt2,
                                                    const float* __restrict__ cA2,
                                                    const float* __restrict__ CB,
                                                    const float* __restrict__ prevT,
                                                    const float* __restrict__ Dp,
                                                    u16* __restrict__ Y) {
  __shared__ __align__(16) u16 Ms[256 * LDM];
  __shared__ __align__(16) u16 Xt[64 * LDM];
  __shared__ float cas[256];
  __shared__ float dts[256];
  const int c = blockIdx.x, h = blockIdx.y;
  const int tid = threadIdx.x;
  const int lane = tid & 63;
  const int w = tid >> 6;
  const int fr = lane & 15, q = lane >> 4;

  cas[tid] = cA2[h * 2048 + c * 256 + tid];
  dts[tid] = dt2[h * 2048 + c * 256 + tid];

  f32x4 acc[4][4];
#pragma unroll
  for (int i = 0; i < 4; ++i)
#pragma unroll
    for (int j = 0; j < 4; ++j) acc[i][j] = (f32x4){0.f, 0.f, 0.f, 0.f};

  const int sg = (tid & 7) * 8;
  const int lb = tid >> 3;
  const int xp = tid & 63;
  const int xq = tid >> 6;

  __syncthreads();

  for (int kt = 0; kt < 6; ++kt) {
    __syncthreads();
    if (kt < 4) {
      const int s0 = kt * 64;
      f32x4 e0 = *(const f32x4*)&cas[s0 + sg];
      f32x4 e1 = *(const f32x4*)&cas[s0 + sg + 4];
      f32x4 d0 = *(const f32x4*)&dts[s0 + sg];
      f32x4 d1 = *(const f32x4*)&dts[s0 + sg + 4];
#pragma unroll
      for (int k = 0; k < 8; ++k) {
        const int l = lb + 32 * k;
        const float cal = cas[l];
        const float* cb = CB + (long)c * 65536 + (long)l * 256 + s0 + sg;
        f32x4 c0 = *(const f32x4*)cb;
        f32x4 c1 = *(const f32x4*)(cb + 4);
        union { u16 u[8]; bf16x8 v; } pk;
#pragma unroll
        for (int u = 0; u < 8; ++u) {
          int s = s0 + sg + u;
          float cv = (u < 4) ? c0[u] : c1[u - 4];
          float cs = (u < 4) ? e0[u] : e1[u - 4];
          float dv = (u < 4) ? d0[u] : d1[u - 4];
          float m = (s <= l) ? cv * __expf(cal - cs) * dv : 0.f;
          pk.u[u] = f2bf(m);
        }
        *(bf16x8*)(Ms + l * LDM + sg) = pk.v;
      }
#pragma unroll
      for (int r = 0; r < 2; ++r) {
        int p = (tid >> 3) + 32 * r;
        *(bf16x8*)(Xt + p * LDM + sg) =
            *(const bf16x8*)(xT + (long)(h * 64 + p) * 2048 + c * 256 + s0 + sg);
      }
    } else {
      const int n0 = (kt - 4) * 64;
#pragma unroll
      for (int k = 0; k < 8; ++k) {
        const int l = lb + 32 * k;
        const float ea = __expf(cas[l]);
        u16x8 raw = *(const u16x8*)(xbf + (long)(c * 256 + l) * CONVD + 4224 + n0 + sg);
        union { u16 u[8]; bf16x8 v; } pk;
#pragma unroll
        for (int u = 0; u < 8; ++u) pk.u[u] = f2bf(ea * bf2f(raw[u]));
        *(bf16x8*)(Ms + l * LDM + sg) = pk.v;
      }
      const float* pT = prevT + (long)(c * 64 + h) * 8192;
#pragma unroll
      for (int half = 0; half < 2; ++half) {
        const int nb2 = xq * 16 + half * 8;
        union { u16 u[8]; bf16x8 v; } pk;
#pragma unroll
        for (int u = 0; u < 8; ++u) pk.u[u] = f2bf(pT[(n0 + nb2 + u) * 64 + xp]);
        *(bf16x8*)(Xt + xp * LDM + nb2) = pk.v;
      }
    }
    __syncthreads();
#pragma unroll
    for (int ks = 0; ks < 64; ks += 32) {
      bf16x8 af[4], bfv[4];
#pragma unroll
      for (int i = 0; i < 4; ++i)
        af[i] = *(const bf16x8*)(Ms + (w * 64 + i * 16 + fr) * LDM + ks + q * 8);
#pragma unroll
      for (int j = 0; j < 4; ++j)
        bfv[j] = *(const bf16x8*)(Xt + (j * 16 + fr) * LDM + ks + q * 8);
#pragma unroll
      for (int i = 0; i < 4; ++i)
#pragma unroll
        for (int j = 0; j < 4; ++j)
          acc[i][j] = __builtin_amdgcn_mfma_f32_16x16x32_bf16(af[i], bfv[j], acc[i][j], 0, 0, 0);
    }
  }

  const int cr = (lane >> 4) * 4;
  const int cc = lane & 15;
  const float dh = Dp[h];
#pragma unroll
  for (int i = 0; i < 4; ++i)
#pragma unroll
    for (int j = 0; j < 4; ++j) {
      const int p = j * 16 + cc;
#pragma unroll
      for (int t = 0; t < 4; ++t) {
        const int row = w * 64 + i * 16 + cr + t;
        const float xv = bf2f(xbf[(long)(c * 256 + row) * CONVD + h * 64 + p]);
        Y[(long)(c * 256 + row) * 4096 + h * 64 + p] = f2bf(acc[i][j][t] + dh * xv);
      }
    }
}

// ---------- gated RMSNorm (Y in bf16) -> bf16 z ----------
__global__ __launch_bounds__(256) void rmsnorm_kernel(const u16* __restrict__ Y,
                                                      const float* __restrict__ proj,
                                                      const float* __restrict__ nw,
                                                      u16* __restrict__ zbf) {
  __shared__ float red[256];
  int t = blockIdx.x, tid = threadIdx.x;
  const u16* y = Y + (long)t * 4096;
  const float* g = proj + (long)t * LDP;
  float zv[16];
  float s = 0.f;
#pragma unroll
  for (int k = 0; k < 16; ++k) {
    int i = tid + k * 256;
    float gv = g[i];
    float z = bf2f(y[i]) * (gv / (1.f + __expf(-gv)));
    zv[k] = z;
    s += z * z;
  }
  red[tid] = s;
  __syncthreads();
  if (tid < 128) red[tid] += red[tid + 128];
  __syncthreads();
  if (tid < 64) {
    float v = red[tid] + red[tid + 64];
    v += __shfl_down(v, 32);
    v += __shfl_down(v, 16);
    v += __shfl_down(v, 8);
    v += __shfl_down(v, 4);
    v += __shfl_down(v, 2);
    v += __shfl_down(v, 1);
    if (tid == 0) red[0] = v;
  }
  __syncthreads();
  float scale = rsqrtf(red[0] * (1.f / 4096.f) + 1e-5f);
#pragma unroll
  for (int k = 0; k < 16; ++k) {
    int i = tid + k * 256;
    zbf[(long)t * 4096 + i] = f2bf(zv[k] * scale * nw[i]);
  }
}

// ---------- launch ----------
extern "C" void kernel_launch(void* const* d_in, const int* in_sizes, int n_in,
                              void* d_out, int out_size, void* d_ws, size_t ws_size,
                              hipStream_t stream) {
  const float* hidden = (const float*)d_in[0];
  const float* Win    = (const float*)d_in[1];
  const float* convw  = (const float*)d_in[2];
  const float* convb  = (const float*)d_in[3];
  const float* dtb    = (const float*)d_in[4];
  const float* Ap     = (const float*)d_in[5];
  const float* Dp     = (const float*)d_in[6];
  const float* nw     = (const float*)d_in[7];
  const float* Wout   = (const float*)d_in[8];
  float* out = (float*)d_out;
  char* ws = (char*)d_ws;

  // workspace layout (bytes); Y overlays hb+WinT; GEMM2 partials overlay proj
  u16*   hb    = (u16*)(ws + 0);            //  8,388,608
  u16*   WinT  = (u16*)(ws + 8388608L);     // 35,127,296  [8576][2048] bf16
  float* proj  = (float*)(ws + 43515904L);  // 70,254,592  [2048][8576] f32
  u16*   WoutT = (u16*)(ws + 113770496L);   // 16,777,216  [2048][4096] bf16
  u16*   xbf   = (u16*)(ws + 130547712L);   // 17,825,792  [2048][4352] bf16
  u16*   xT    = (u16*)(ws + 148373504L);   // 17,301,504  [4224][2048] bf16
  float* dt2   = (float*)(ws + 165675008L); //    524,288  [64][2048]
  float* cA2   = (float*)(ws + 166199296L); //    524,288  [64][2048]
  float* CBv   = (float*)(ws + 166723584L); //  2,097,152  [8][256][256]
  float* stT   = (float*)(ws + 168820736L); // 16,777,216  [8][64][128][64]
  float* prevT = (float*)(ws + 185597952L); // 16,777,216
  u16*   zbf   = (u16*)(ws + 202375168L);   // 16,777,216  [2048][4096] bf16
  u16*   Y     = (u16*)(ws + 0);            // 16,777,216  [2048][4096] bf16 (overlay)
  float* Cp    = (float*)(ws + 43515904L);  // 33,554,432  GEMM2 partials (overlay proj)

  cvt_bf16<<<4096, 256, 0, stream>>>(hidden, hb, 1048576);
  transpose_bf16<<<dim3(268, 64), dim3(32, 8), 0, stream>>>(Win, WinT, 2048, 8512);
  transpose_bf16<<<dim3(64, 128), dim3(32, 8), 0, stream>>>(Wout, WoutT, 4096, 2048);
  gemm_bt<<<dim3(67, 16, 1), 256, 0, stream>>>(hb, WinT, proj, 8576, 2048, 2048, 0L);
  conv_silu_t<<<dim3(136, 64), 256, 0, stream>>>(proj, convw, convb, xbf, xT);
  dt_cumsum<<<dim3(8, 64), 256, 0, stream>>>(proj, dtb, Ap, dt2, cA2);
  cb_gemm<<<dim3(2, 2, 8), 256, 0, stream>>>(xbf, CBv);
  states_kernel<<<dim3(8, 64), 256, 0, stream>>>(xT, dt2, cA2, stT);
  scan_kernel<<<2048, 256, 0, stream>>>(stT, cA2, prevT);
  ssm_y_kernel<<<dim3(8, 64), 256, 0, stream>>>(xbf, xT, dt2, cA2, CBv, prevT, Dp, Y);
  rmsnorm_kernel<<<2048, 256, 0, stream>>>(Y, proj, nw, zbf);
  gemm_bt<<<dim3(16, 16, 2), 256, 0, stream>>>(zbf, WoutT, Cp, 2048, 4096, 2048, 4194304L);
  add2_kernel<<<4096, 256, 0, stream>>>(Cp, Cp + 4194304, out);
}